// Round 7
// baseline (736.917 us; speedup 1.0000x reference)
//
#include <hip/hip_runtime.h>
#include <hip/hip_bf16.h>
#include <cstdint>
#include <cstddef>
#include <math.h>

// Match numpy f32 per-op rounding: no FMA contraction, no reassociation.
// (fmaf() below is explicit and unaffected by the pragma.)
#pragma clang fp contract(off)

#define A_N 8732
#define C_N 91
#define CM1 90
#define B_N 32
#define TOPK 400
#define MAXDET 200
#define NT 512                              /* threads in k_topknms */
#define CCAP 1024                           /* candidate-list capacity */
#define BBOX_CLIPF 4.135166556742356f       /* log(1000/16) cast to f32 */

// Exact predicate constant: for c = 0.45f (even mantissa),
// RN(x/y) > c  <=>  x > (c + 2^-26)*y  with the product exact in double
// (25-bit * 24-bit mantissa). Bit-equivalent to the IEEE f32 divide+compare.
#define IOU_M ((double)0.45f + 0x1p-26)

// 16B vector of floats with only 4B alignment guarantee (rows are 91 floats,
// so row bases are 4B- but not 16B-aligned).
typedef float f4u __attribute__((ext_vector_type(4), aligned(4)));

// Dual-path input load (reference is float32; sniff is insurance).
__device__ __forceinline__ float ldin(const void* p, size_t i, int isbf16) {
    if (isbf16) return __bfloat162float(((const __hip_bfloat16*)p)[i]);
    return ((const float*)p)[i];
}

// numpy SIMD f32 exp — bit-faithful (PROVEN bit-exact, absmax 0.0).
// DO NOT alter any constant or association.
__device__ __forceinline__ float np_expf(float x) {
    float q = rintf(x * 1.442695040f);
    float r = fmaf(q, -0.693359375f, x);
    r = fmaf(q, 2.12194440e-4f, r);
    float p = 1.9875691500E-4f;
    p = fmaf(p, r, 1.3981999507E-3f);
    p = fmaf(p, r, 8.3334519073E-3f);
    p = fmaf(p, r, 4.1665795894E-2f);
    p = fmaf(p, r, 1.6666665459E-1f);
    p = fmaf(p, r, 5.0000001201E-1f);
    p = fmaf(p, r, 1.0f);
    p = fmaf(p, r, 1.0f);
    return ldexpf(p, (int)q);
}

// ---------------------------------------------------------------- dtype sniff
__global__ void k_sniff(const unsigned* __restrict__ words, int* __restrict__ flag) {
    __shared__ int cnt_s;
    if (threadIdx.x == 0) cnt_s = 0;
    __syncthreads();
    int local = 0;
    for (int i = threadIdx.x; i < 4096; i += 256) {
        unsigned w = words[i];
        unsigned e = (w >> 7) & 0xFFu;
        if (e >= 100u && e <= 140u) local++;
    }
    atomicAdd(&cnt_s, local);
    __syncthreads();
    if (threadIdx.x == 0) flag[0] = (cnt_s > 2048) ? 1 : 0;
}

// ---------------------------------------------------------------- softmax + score + decode (fused)
// v8: SINGLE pass over the logits row, held in registers (91 floats, static
// indexing). Max chain, np_expf per class, exact numpy pairwise r[8] denom,
// then sc = e/res (same quotient bits the consumer used to compute) masked
// with > 0.01f and stored TRANSPOSED to scT[(b*90+c-1)*A + a]. amax/denom
// still written (fallback path needs them). Decode fused (PROVEN bit-exact).
__global__ void k_stats(const void* __restrict__ logits,
                        const void* __restrict__ rel,
                        const void* __restrict__ anchors,
                        const int* __restrict__ flag,
                        float* __restrict__ amax,
                        float* __restrict__ denom,
                        float* __restrict__ boxes,
                        unsigned* __restrict__ scT) {
    int i = blockIdx.x * blockDim.x + threadIdx.x;
    if (i >= B_N * A_N) return;
    int bf = flag[0];
    size_t base = (size_t)i * C_N;
    int bb = i / A_N, aa = i - bb * A_N;
    unsigned* sbase = scT ? (scT + (size_t)bb * CM1 * A_N + aa) : (unsigned*)0;

    if (!bf) {
        const float* lp = (const float*)logits + base;
        float x[91];
        #pragma unroll
        for (int k = 0; k < 22; ++k) {
            f4u v = *(const f4u*)(lp + 4 * k);
            x[4 * k + 0] = v.x; x[4 * k + 1] = v.y;
            x[4 * k + 2] = v.z; x[4 * k + 3] = v.w;
        }
        x[88] = lp[88]; x[89] = lp[89]; x[90] = lp[90];

        float m = -INFINITY;
        #pragma unroll
        for (int c = 0; c < 91; ++c) m = fmaxf(m, x[c]);

        #pragma unroll
        for (int c = 0; c < 91; ++c) x[c] = np_expf(x[c] - m);   // x := e

        // exact numpy pairwise: r[j] = sum_k e[8k+j], k ascending (as before)
        float r[8];
        #pragma unroll
        for (int j = 0; j < 8; ++j) {
            float s = x[j];
            #pragma unroll
            for (int k = 1; k < 11; ++k) s += x[8 * k + j];
            r[j] = s;
        }
        float res = ((r[0] + r[1]) + (r[2] + r[3])) + ((r[4] + r[5]) + (r[6] + r[7]));
        res += x[88]; res += x[89]; res += x[90];
        amax[i]  = m;
        denom[i] = res;

        if (sbase) {
            #pragma unroll
            for (int c = 1; c < 91; ++c) {
                float sc = x[c] / res;       // identical quotient bits to the
                                             // consumer's old e/denom divide
                sbase[(size_t)(c - 1) * A_N] =
                    (sc > 0.01f) ? __float_as_uint(sc) : 0u;
            }
        }
    } else {
        // bf16 insurance path — scalar, same proven structure; emits sc bits.
        float m = -INFINITY;
        for (int c = 0; c < C_N; ++c) m = fmaxf(m, ldin(logits, base + c, bf));
        float r[8];
        for (int j = 0; j < 8; ++j) r[j] = np_expf(ldin(logits, base + j, bf) - m);
        for (int c = 8; c < 88; c += 8)
            for (int j = 0; j < 8; ++j) r[j] += np_expf(ldin(logits, base + c + j, bf) - m);
        float res = ((r[0] + r[1]) + (r[2] + r[3])) + ((r[4] + r[5]) + (r[6] + r[7]));
        res += np_expf(ldin(logits, base + 88, bf) - m);
        res += np_expf(ldin(logits, base + 89, bf) - m);
        res += np_expf(ldin(logits, base + 90, bf) - m);
        amax[i]  = m;
        denom[i] = res;
        if (sbase) {
            for (int c = 1; c < C_N; ++c) {
                float sc = np_expf(ldin(logits, base + c, bf) - m) / res;
                sbase[(size_t)(c - 1) * A_N] =
                    (sc > 0.01f) ? __float_as_uint(sc) : 0u;
            }
        }
    }

    // ---- fused box decode (PROVEN bit-exact expressions) ----
    {
        int a = aa;
        float ax1, ay1, ax2, ay2, r0, r1, r2, r3;
        if (!bf) {
            float4 av = ((const float4*)anchors)[a];
            float4 rv = ((const float4*)rel)[i];
            ax1 = av.x; ay1 = av.y; ax2 = av.z; ay2 = av.w;
            r0 = rv.x; r1 = rv.y; r2 = rv.z; r3 = rv.w;
        } else {
            ax1 = ldin(anchors, (size_t)a * 4 + 0, bf);
            ay1 = ldin(anchors, (size_t)a * 4 + 1, bf);
            ax2 = ldin(anchors, (size_t)a * 4 + 2, bf);
            ay2 = ldin(anchors, (size_t)a * 4 + 3, bf);
            r0 = ldin(rel, (size_t)i * 4 + 0, bf);
            r1 = ldin(rel, (size_t)i * 4 + 1, bf);
            r2 = ldin(rel, (size_t)i * 4 + 2, bf);
            r3 = ldin(rel, (size_t)i * 4 + 3, bf);
        }
        float wa = ax2 - ax1, ha = ay2 - ay1;
        float cxa = ax1 + 0.5f * wa, cya = ay1 + 0.5f * ha;
        float dx = r0 / 10.0f, dy = r1 / 10.0f;
        float dw = fminf(r2 / 5.0f, BBOX_CLIPF);
        float dh = fminf(r3 / 5.0f, BBOX_CLIPF);
        float cx = dx * wa + cxa, cy = dy * ha + cya;
        float w = np_expf(dw) * wa, h = np_expf(dh) * ha;
        float4 o;
        o.x = fminf(fmaxf(cx - 0.5f * w, 0.0f), 300.0f);
        o.y = fminf(fmaxf(cy - 0.5f * h, 0.0f), 300.0f);
        o.z = fminf(fmaxf(cx + 0.5f * w, 0.0f), 300.0f);
        o.w = fminf(fmaxf(cy + 0.5f * h, 0.0f), 300.0f);
        ((float4*)boxes)[i] = o;
    }
}

// ---------------------------------------------------------------- fused top-400 + per-class NMS
// v8: scT holds masked SCORE bits (no denom loads, no divides here). Select
// fast path: if strictly-greater + boundary-bucket entries fit in 512, sort
// desc == exact selection + tie rule (skips levels 2/3). NMS: pipelined
// ballot mask build + tight ctz/shfl scan (same keep decisions).
__global__ __launch_bounds__(NT) void k_topknms_pre(const unsigned* __restrict__ scT,
                                                    const float* __restrict__ boxes,
                                                    unsigned long long* __restrict__ kkey,
                                                    int* __restrict__ kcnt) {
    __shared__ __align__(16) float4 nbq[TOPK];      // 6400 B
    __shared__ float sar[TOPK];                     // 1600 B
    __shared__ unsigned long long wlist[512];       // 4096 B
    __shared__ unsigned long long cand[CCAP];       // 8192 B
    __shared__ unsigned hist[1024];                 // 4096 B
    __shared__ unsigned long long fsup[8];
    __shared__ unsigned long long ksv[8];
    __shared__ unsigned sel_b;
    __shared__ int sel_rem;
    __shared__ int nreal_s;
    __shared__ int eqlist[64];
    __shared__ int eqn, nsel, candn, total_s;

    int bc = blockIdx.x;
    int b  = bc / CM1;
    int cm = bc % CM1;                       // class row 0..89 (logit col cm+1)
    int t  = threadIdx.x;

    const unsigned* srow = scT + (size_t)bc * A_N;
    const uint4* srow4 = (const uint4*)srow;

    // ---- phase 0: stream masked score bits, build level-1 histogram.
    if (t == 0) { eqn = 0; nsel = 0; candn = 0; total_s = 0; }
    for (int q = t; q < 1024; q += NT) hist[q] = 0u;
    __syncthreads();
    for (int k = t; k < A_N / 4; k += NT) {
        uint4 v = srow4[k];
        if (v.x) atomicAdd(&hist[(v.x >> 16) & 0x3FFu], 1u);
        if (v.y) atomicAdd(&hist[(v.y >> 16) & 0x3FFu], 1u);
        if (v.z) atomicAdd(&hist[(v.z >> 16) & 0x3FFu], 1u);
        if (v.w) atomicAdd(&hist[(v.w >> 16) & 0x3FFu], 1u);
    }
    __syncthreads();

    // ---- level-1 scan: suffix sums give BOTH nreal and the 400th bucket.
    if (t < 64) {
        unsigned s = 0;
        #pragma unroll
        for (int q = 0; q < 16; ++q) s += hist[16 * t + q];
        unsigned suf = s;
        for (int o = 1; o < 64; o <<= 1) {
            unsigned vv = __shfl_down(suf, o);
            if (t + o < 64) suf += vv;
        }
        if (t == 0) nreal_s = (int)suf;
        unsigned cum = suf - s;
        for (int q = 15; q >= 0; --q) {
            unsigned h = hist[16 * t + q];
            if ((int)cum < TOPK && TOPK <= (int)(cum + h)) {
                sel_b = (unsigned)(16 * t + q);
                sel_rem = TOPK - (int)cum;
            }
            cum += h;
        }
    }
    __syncthreads();
    int nreal = nreal_s;
    bool sel_path = (nreal >= TOPK);         // block-uniform
    unsigned selL1 = sel_b;                  // valid iff sel_path
    unsigned prefix1 = (0xFu << 10) | selL1;
    __syncthreads();

    // ---- pass B: classify. bucket>selL1 -> wlist; bucket==selL1 -> cand
    // (+ level-2 histogram for the slow path); !sel_path: all nonzero -> wlist.
    if (sel_path) { for (int q = t; q < 1024; q += NT) hist[q] = 0u; }
    __syncthreads();
    for (int k = t; k < A_N / 4; k += NT) {
        uint4 vv = srow4[k];
        unsigned va[4] = {vv.x, vv.y, vv.z, vv.w};
        #pragma unroll
        for (int c = 0; c < 4; ++c) {
            unsigned v = va[c];
            if (!v) continue;
            unsigned a = (unsigned)(4 * k + c);
            if (sel_path) {
                unsigned bkt = (v >> 16) & 0x3FFu;
                if (bkt > selL1) {
                    int slot = atomicAdd(&nsel, 1);
                    if (slot < 512)
                        wlist[slot] = ((unsigned long long)v << 32) | (unsigned)(~a);
                } else if (bkt == selL1) {
                    int s2 = atomicAdd(&candn, 1);
                    if (s2 < CCAP)
                        cand[s2] = ((unsigned long long)v << 32) | (unsigned)(~a);
                    atomicAdd(&hist[(v >> 6) & 0x3FFu], 1u);
                }
            } else {
                int slot = atomicAdd(&nsel, 1);
                if (slot < 512)
                    wlist[slot] = ((unsigned long long)v << 32) | (unsigned)(~a);
            }
        }
    }
    __syncthreads();

    if (sel_path) {
        int ngt = nsel;                      // strictly-greater count (<400)
        int cn  = candn;                     // boundary-bucket count
        bool fast = (cn <= CCAP) && (ngt + cn <= 512);
        if (fast) {
            // exact: sort of (gt ∪ bucket) desc by (score, anchor asc) and
            // truncation to 400 == proven selection + tie rule.
            for (int q = t; q < cn; q += NT) wlist[ngt + q] = cand[q];
            __syncthreads();
            if (t == 0) nsel = ngt + cn;
            __syncthreads();
        } else {
            // ---- slow path (verbatim r6 logic, recompute-free) ----
            bool ovf = (cn > CCAP);
            if (t < 64) {
                int rem = sel_rem;
                unsigned s = 0;
                #pragma unroll
                for (int q = 0; q < 16; ++q) s += hist[16 * t + q];
                unsigned suf = s;
                for (int o = 1; o < 64; o <<= 1) {
                    unsigned vv = __shfl_down(suf, o);
                    if (t + o < 64) suf += vv;
                }
                unsigned cum = suf - s;
                for (int q = 15; q >= 0; --q) {
                    unsigned h = hist[16 * t + q];
                    if ((int)cum < rem && rem <= (int)(cum + h)) {
                        sel_b = (unsigned)(16 * t + q);
                        sel_rem = rem - (int)cum;
                    }
                    cum += h;
                }
            }
            __syncthreads();
            unsigned prefix2 = (prefix1 << 10) | sel_b;

            if (t < 64) hist[t] = 0u;
            __syncthreads();
            if (!ovf) {
                int cc = cn < CCAP ? cn : CCAP;
                for (int q = t; q < cc; q += NT) {
                    unsigned v = (unsigned)(cand[q] >> 32);
                    if ((v >> 6) == prefix2) atomicAdd(&hist[v & 0x3Fu], 1u);
                }
            } else {
                for (int a = t; a < A_N; a += NT) {
                    unsigned v = srow[a];
                    if (v && (v >> 6) == prefix2) atomicAdd(&hist[v & 0x3Fu], 1u);
                }
            }
            __syncthreads();
            if (t == 0) {
                int rem = sel_rem;
                unsigned cum = 0;
                for (int bq = 63; bq >= 0; --bq) {
                    unsigned h = hist[bq];
                    if ((int)cum < rem && rem <= (int)(cum + h)) {
                        sel_b = (unsigned)bq;
                        sel_rem = rem - (int)cum;
                        break;
                    }
                    cum += h;
                }
            }
            __syncthreads();
            unsigned sstar = (prefix2 << 6) | sel_b;
            int teq = sel_rem;

            if (!ovf) {
                int cc = cn < CCAP ? cn : CCAP;
                for (int q = t; q < cc; q += NT) {
                    unsigned long long cv = cand[q];
                    unsigned v = (unsigned)(cv >> 32);
                    if (v > sstar) {
                        int slot = atomicAdd(&nsel, 1);
                        if (slot < 512) wlist[slot] = cv;
                    } else if (v == sstar) {
                        int s2 = atomicAdd(&eqn, 1);
                        if (s2 < 64) eqlist[s2] = (int)(~(unsigned)cv);
                    }
                }
            } else {
                for (int a = t; a < A_N; a += NT) {
                    unsigned v = srow[a];
                    if (!v) continue;
                    if ((v >> 16) == prefix1) {
                        if (v > sstar) {
                            int slot = atomicAdd(&nsel, 1);
                            if (slot < 512)
                                wlist[slot] = ((unsigned long long)v << 32) |
                                              (unsigned)(~(unsigned)a);
                        } else if (v == sstar) {
                            int s2 = atomicAdd(&eqn, 1);
                            if (s2 < 64) eqlist[s2] = a;
                        }
                    }
                }
            }
            __syncthreads();
            if (t == 0) {
                int n = eqn < 64 ? eqn : 64; // same 64-cap as proven kernel
                for (int i2 = 1; i2 < n; ++i2) {
                    int v2 = eqlist[i2], j2 = i2 - 1;
                    while (j2 >= 0 && eqlist[j2] > v2) { eqlist[j2 + 1] = eqlist[j2]; --j2; }
                    eqlist[j2 + 1] = v2;
                }
                int tq = teq < n ? teq : n;
                int bse = nsel;
                for (int q2 = 0; q2 < tq; ++q2) {
                    int slot = bse + q2;
                    if (slot < 512)
                        wlist[slot] = ((unsigned long long)sstar << 32) |
                                      (unsigned)(~(unsigned)eqlist[q2]);
                }
                nsel = bse + tq;
            }
            __syncthreads();
        }
    }
    int ns = nsel < 512 ? nsel : 512;
    if (t >= ns) wlist[t] = 0ull;
    __syncthreads();

    // ---- bitonic sort 512 desc, register-resident; shfl_xor for j<=32,
    // LDS exchange only for j>=64. Same network => identical permutation.
    {
        unsigned long long u = wlist[t];
        for (int k = 2; k <= 512; k <<= 1) {
            bool up = ((t & k) == 0);
            for (int j = k >> 1; j >= 64; j >>= 1) {
                __syncthreads();
                wlist[t] = u;
                __syncthreads();
                unsigned long long v = wlist[t ^ j];
                bool takeMax = (((t & j) == 0) == up);
                u = takeMax ? (u > v ? u : v) : (u < v ? u : v);
            }
            for (int j = ((k >> 1) < 64 ? (k >> 1) : 32); j > 0; j >>= 1) {
                unsigned long long v = __shfl_xor(u, j);
                bool takeMax = (((t & j) == 0) == up);
                u = takeMax ? (u > v ? u : v) : (u < v ? u : v);
            }
        }
        __syncthreads();
        wlist[t] = u;
        __syncthreads();
    }

    // ---- per-class NMS on the sorted top-400 ----
    int m = ns < TOPK ? ns : TOPK;
    float offc = (float)(cm + 1) * 301.0f;
    if (t < m) {
        unsigned aidx = ~(unsigned)(wlist[t] & 0xFFFFFFFFull);
        const float* bp = boxes + ((size_t)b * A_N + aidx) * 4;
        float4 q;
        q.x = bp[0] + offc; q.y = bp[1] + offc;   // same exprs as proven code
        q.z = bp[2] + offc; q.w = bp[3] + offc;
        nbq[t] = q;
        sar[t] = (q.z - q.x) * (q.w - q.y);       // == bar[t] bits
    }
    if (t < 8) { fsup[t] = 0ull; ksv[t] = 0ull; }
    __syncthreads();

    int nch = (m + 63) >> 6;
    for (int g = 0; g < nch; ++g) {
        // wave 0: pipelined in-chunk mask build (independent iterations),
        // then tight ctz/shfl greedy scan. Keep decisions identical to the
        // proven serial scan (suppressed rows' masks are built but never OR'd).
        if (t < 64) {
            int bse = 64 * g;
            int jmax = m - bse; if (jmax > 64) jmax = 64;
            bool valid = t < jmax;
            float4 cb = valid ? nbq[bse + t] : make_float4(0.f, 0.f, 0.f, 0.f);
            float car = valid ? sar[bse + t] : 0.0f;
            unsigned long long w = 0ull;
            for (int j = 0; j < jmax; ++j) {          // pipelined build
                float rx1 = __shfl(cb.x, j), ry1 = __shfl(cb.y, j);
                float rx2 = __shfl(cb.z, j), ry2 = __shfl(cb.w, j);
                float ra  = __shfl(car, j);
                bool p = false;
                if (valid && t > j) {
                    float lx = fmaxf(rx1, cb.x), ly = fmaxf(ry1, cb.y);
                    float rx = fminf(rx2, cb.z), ry = fminf(ry2, cb.w);
                    float ww = fmaxf(rx - lx, 0.0f), hh = fmaxf(ry - ly, 0.0f);
                    float inter = ww * hh;
                    float U = ra + car - inter + 1e-9f;   // row area first
                    p = ((double)inter > IOU_M * (double)U);
                }
                unsigned long long bj = __ballot(p);
                if (t == j) w = bj;                   // lane j keeps row j's word
            }
            unsigned long long sup = fsup[g], kv = 0ull;
            unsigned long long rem =
                ((jmax == 64) ? ~0ull : ((1ull << jmax) - 1ull)) & ~sup;
            while (rem) {                             // tight scan
                int j = __builtin_ctzll(rem);
                unsigned long long wj = __shfl(w, j);
                kv |= 1ull << j;
                sup |= wj;
                rem &= ~(sup | (1ull << j));
            }
            if (t == 0) { ksv[g] = kv; total_s += __popcll(kv); }
        }
        __syncthreads();
        if (total_s >= MAXDET) break;        // uniform; rows past the 200th
                                             // kept are never emitted anyway
        if (g + 1 < nch) {
            // waves 1..: future-word suppression = OR over kept rows of
            // chunk g (broadcast LDS reads; lane = column of word h).
            int w = t >> 6, l = t & 63;
            int h = g + 1 + w;
            if (h < nch) {
                unsigned long long kv = ksv[g];
                int jmax2 = m - 64 * h; if (jmax2 > 64) jmax2 = 64;
                bool v2 = l < jmax2;
                float4 cbl = v2 ? nbq[64 * h + l] : make_float4(0.f, 0.f, 0.f, 0.f);
                float cal = v2 ? sar[64 * h + l] : 0.0f;
                bool acc = false;
                unsigned long long rr = kv;
                while (rr) {
                    int r = __builtin_ctzll(rr); rr &= rr - 1;
                    float4 rq = nbq[64 * g + r];     // wave-uniform broadcast
                    float rar = sar[64 * g + r];
                    if (v2 && !acc) {
                        float lx = fmaxf(rq.x, cbl.x), ly = fmaxf(rq.y, cbl.y);
                        float rx = fminf(rq.z, cbl.z), ry = fminf(rq.w, cbl.w);
                        float ww = fmaxf(rx - lx, 0.0f), hh = fmaxf(ry - ly, 0.0f);
                        float inter = ww * hh;
                        float U = rar + cal - inter + 1e-9f;
                        acc = ((double)inter > IOU_M * (double)U);
                    }
                }
                unsigned long long wd = __ballot(acc);
                if (l == 0) fsup[h] |= wd;
            }
        }
        __syncthreads();
    }

    // rank-parallel emission (kept order == row order == serial order)
    if (t < 64) {
        int l = t, basek = 0;
        for (int g = 0; g < nch; ++g) {
            unsigned long long kv = ksv[g];
            int row = 64 * g + l;
            if ((kv >> l) & 1ull) {
                int rank = basek + __popcll(kv & ((1ull << l) - 1ull));
                if (rank < MAXDET) {
                    unsigned long long wv = wlist[row];
                    unsigned sbts = (unsigned)(wv >> 32);
                    unsigned aa2  = ~(unsigned)wv;        // anchor, <16384
                    int flat = cm * TOPK + row;
                    unsigned long long key =
                        ((unsigned long long)sbts << 31) |
                        ((unsigned long long)(131071 - flat) << 14) |
                        (unsigned long long)aa2;
                    kkey[(size_t)bc * MAXDET + rank] = key;
                }
            }
            basek += __popcll(kv);
        }
        if (l == 0) kcnt[bc] = total_s < MAXDET ? total_s : MAXDET;
    }
}

// ---------------------------------------------------------------- FALLBACK top-400 + NMS
// Verbatim proven kernel (used only if the workspace can't hold scT).
__global__ __launch_bounds__(NT) void k_topknms(const void* __restrict__ logits,
                                                const int* __restrict__ flag,
                                                const float* __restrict__ amax,
                                                const float* __restrict__ denom,
                                                const float* __restrict__ boxes,
                                                unsigned long long* __restrict__ kkey,
                                                int* __restrict__ kcnt) {
    __shared__ union {
        unsigned sbits[A_N];
        unsigned long long msk[TOPK * 7];
    } su;
    __shared__ unsigned long long wlist[512];
    __shared__ float bx1[TOPK], by1[TOPK], bx2[TOPK], by2[TOPK], bar[TOPK];
    __shared__ int wred[NT / 64];
    __shared__ unsigned bcast_p;
    __shared__ int bcast_rem;
    __shared__ int eqlist[64];
    __shared__ int eqn;
    __shared__ int bcast_athr;
    __shared__ int nsel;

    int bc = blockIdx.x;
    int b  = bc / CM1;
    int cm = bc % CM1;
    int bf = flag[0];
    int t  = threadIdx.x;

    for (int a = t; a < A_N; a += NT) {
        size_t base = (size_t)b * A_N + a;
        float e  = np_expf(ldin(logits, base * C_N + (cm + 1), bf) - amax[base]);
        float sc = e / denom[base];
        su.sbits[a] = (sc > 0.01f) ? __float_as_uint(sc) : 0u;
    }
    if (t == 0) { eqn = 0; nsel = 0; }
    __syncthreads();

    {
        int c0 = 0;
        for (int a = t; a < A_N; a += NT) c0 += (su.sbits[a] != 0u);
        for (int o = 32; o; o >>= 1) c0 += __shfl_down(c0, o);
        if ((t & 63) == 0) wred[t >> 6] = c0;
        __syncthreads();
        if (t == 0) {
            int tot = 0;
            for (int wv = 0; wv < NT / 64; ++wv) tot += wred[wv];
            bcast_rem = tot;
        }
        __syncthreads();
    }
    int nreal = bcast_rem;
    __syncthreads();

    unsigned sstar = 0u;
    int teq = 0;
    if (nreal >= TOPK) {
        unsigned p = 0x3C000000u;
        int rem = TOPK;
        for (int bit = 25; bit >= 0; --bit) {
            unsigned q = p | (1u << bit);
            int cnt = 0;
            for (int a = t; a < A_N; a += NT) cnt += ((su.sbits[a] >> bit) == (q >> bit));
            for (int o = 32; o; o >>= 1) cnt += __shfl_down(cnt, o);
            if ((t & 63) == 0) wred[t >> 6] = cnt;
            __syncthreads();
            if (t == 0) {
                int tot = 0;
                for (int wv = 0; wv < NT / 64; ++wv) tot += wred[wv];
                if (tot >= rem) { bcast_p = q; bcast_rem = rem; }
                else            { bcast_p = p; bcast_rem = rem - tot; }
            }
            __syncthreads();
            p = bcast_p; rem = bcast_rem;
            __syncthreads();
        }
        sstar = p;
        teq = rem;
        for (int a = t; a < A_N; a += NT) {
            if (su.sbits[a] == sstar) {
                int slot = atomicAdd(&eqn, 1);
                if (slot < 64) eqlist[slot] = a;
            }
        }
        __syncthreads();
        if (t == 0) {
            int n = eqn < 64 ? eqn : 64;
            for (int i = 1; i < n; ++i) {
                int v = eqlist[i], j = i - 1;
                while (j >= 0 && eqlist[j] > v) { eqlist[j + 1] = eqlist[j]; --j; }
                eqlist[j + 1] = v;
            }
            int tq = teq < n ? teq : n;
            bcast_athr = (tq > 0) ? eqlist[tq - 1] : -1;
        }
        __syncthreads();
    }
    int athr = (nreal >= TOPK) ? bcast_athr : -1;
    __syncthreads();

    for (int a = t; a < A_N; a += NT) {
        unsigned v = su.sbits[a];
        bool sel;
        if (nreal >= TOPK)
            sel = (v > sstar) || (v == sstar && a <= athr);
        else
            sel = (v != 0u);
        if (sel) {
            int slot = atomicAdd(&nsel, 1);
            if (slot < 512)
                wlist[slot] = ((unsigned long long)v << 32) | (unsigned)(~(unsigned)a);
        }
    }
    __syncthreads();
    int ns = nsel < 512 ? nsel : 512;
    if (t < 512 && t >= ns) wlist[t] = 0ull;
    __syncthreads();

    for (int k = 2; k <= 512; k <<= 1) {
        for (int j = k >> 1; j > 0; j >>= 1) {
            int ixj = t ^ j;
            if (ixj > t) {
                unsigned long long u = wlist[t], v = wlist[ixj];
                bool desc = ((t & k) == 0);
                if (desc ? (u < v) : (u > v)) { wlist[t] = v; wlist[ixj] = u; }
            }
            __syncthreads();
        }
    }

    int m = ns < TOPK ? ns : TOPK;
    float offc = (float)(cm + 1) * 301.0f;
    if (t < m) {
        unsigned aidx = ~(unsigned)(wlist[t] & 0xFFFFFFFFull);
        const float* bp = boxes + ((size_t)b * A_N + aidx) * 4;
        float x1 = bp[0] + offc, y1 = bp[1] + offc;
        float x2 = bp[2] + offc, y2 = bp[3] + offc;
        bx1[t] = x1; by1[t] = y1; bx2[t] = x2; by2[t] = y2;
        bar[t] = (x2 - x1) * (y2 - y1);
    }
    __syncthreads();

    if (t < m) {
        unsigned long long w[7] = {0, 0, 0, 0, 0, 0, 0};
        float x1 = bx1[t], y1 = by1[t], x2 = bx2[t], y2 = by2[t], a1 = bar[t];
        for (int j = t + 1; j < m; ++j) {
            float lx = fmaxf(x1, bx1[j]), ly = fmaxf(y1, by1[j]);
            float rx = fminf(x2, bx2[j]), ry = fminf(y2, by2[j]);
            float ww = fmaxf(rx - lx, 0.0f), hh = fmaxf(ry - ly, 0.0f);
            float inter = ww * hh;
            float iou = inter / (a1 + bar[j] - inter + 1e-9f);
            if (iou > 0.45f) w[j >> 6] |= 1ull << (j & 63);
        }
        for (int k2 = 0; k2 < 7; ++k2) su.msk[t * 7 + k2] = w[k2];
    }
    __syncthreads();

    if (t == 0) {
        unsigned long long sup[7] = {0, 0, 0, 0, 0, 0, 0};
        int cnt = 0;
        for (int i = 0; i < m; ++i) {
            if (!((sup[i >> 6] >> (i & 63)) & 1ull)) {
                unsigned long long wv = wlist[i];
                unsigned sb2 = (unsigned)(wv >> 32);
                unsigned a  = ~(unsigned)wv;
                int flat = cm * TOPK + i;
                unsigned long long key =
                    ((unsigned long long)sb2 << 31) |
                    ((unsigned long long)(131071 - flat) << 14) |
                    (unsigned long long)a;
                kkey[(size_t)bc * MAXDET + cnt] = key;
                cnt++;
                if (cnt == MAXDET) break;
                const unsigned long long* r = &su.msk[i * 7];
                for (int k2 = 0; k2 < 7; ++k2) sup[k2] |= r[k2];
            }
        }
        kcnt[bc] = cnt;
    }
}

// ---------------------------------------------------------------- parallel per-image top-200
// Keys are globally unique and each class list is sorted desc, so the merged
// output == the top-200 keys of the union in descending order. Radix select
// of the 200th largest, gather, bitonic sort 256 desc, emit. Bit-identical.
__global__ __launch_bounds__(256) void k_merge(const unsigned long long* __restrict__ kkey,
                                               const int* __restrict__ kcnt,
                                               const float* __restrict__ boxes,
                                               float* __restrict__ out) {
    __shared__ unsigned hist[1024];
    __shared__ unsigned long long wl[256];
    __shared__ int kc[CM1];
    __shared__ int tot_s;
    __shared__ unsigned selb_s;
    __shared__ int selrem_s;
    __shared__ int gcnt;

    int b = blockIdx.x;
    int t = threadIdx.x;
    const unsigned long long* keys = kkey + (size_t)b * (CM1 * MAXDET);
    const float* bx = boxes + (size_t)b * A_N * 4;
    float* ob = out + (size_t)b * MAXDET * 4;
    float* os = out + (size_t)B_N * MAXDET * 4 + (size_t)b * MAXDET;
    float* ol = out + (size_t)B_N * MAXDET * 5 + (size_t)b * MAXDET;

    if (t < CM1) kc[t] = kcnt[b * CM1 + t];
    if (t == 0) { tot_s = 0; gcnt = 0; }
    __syncthreads();

    {
        int c0 = 0;
        for (int idx = t; idx < CM1 * MAXDET; idx += 256) {
            int c = idx / MAXDET;
            if (idx - c * MAXDET < kc[c]) c0++;
        }
        for (int o = 32; o; o >>= 1) c0 += __shfl_down(c0, o);
        if ((t & 63) == 0) atomicAdd(&tot_s, c0);
    }
    __syncthreads();
    int total = tot_s;

    unsigned long long T = 0ull;
    if (total > MAXDET) {
        unsigned long long prefix = 0ull;
        if (t == 0) selrem_s = MAXDET;
        __syncthreads();
        const int sh[7] = {52, 42, 32, 22, 12, 2, 0};
        const int wd[7] = {10, 10, 10, 10, 10, 10, 2};
        for (int l = 0; l < 7; ++l) {
            int shift = sh[l], width = wd[l];
            int nb = 1 << width;
            for (int q = t; q < nb; q += 256) hist[q] = 0u;
            __syncthreads();
            for (int idx = t; idx < CM1 * MAXDET; idx += 256) {
                int c = idx / MAXDET;
                if (idx - c * MAXDET < kc[c]) {
                    unsigned long long key = keys[idx];
                    if ((key >> (shift + width)) == prefix)
                        atomicAdd(&hist[(unsigned)(key >> shift) & (unsigned)(nb - 1)], 1u);
                }
            }
            __syncthreads();
            if (nb >= 64) {
                if (t < 64) {
                    int rem = selrem_s;
                    int per = nb / 64;
                    unsigned s = 0;
                    for (int q = 0; q < per; ++q) s += hist[per * t + q];
                    unsigned suf = s;
                    for (int o = 1; o < 64; o <<= 1) {
                        unsigned vv = __shfl_down(suf, o);
                        if (t + o < 64) suf += vv;
                    }
                    unsigned cum = suf - s;
                    for (int q = per - 1; q >= 0; --q) {
                        unsigned h = hist[per * t + q];
                        if ((int)cum < rem && rem <= (int)(cum + h)) {
                            selb_s = (unsigned)(per * t + q);
                            selrem_s = rem - (int)cum;
                        }
                        cum += h;
                    }
                }
            } else if (t == 0) {
                int rem = selrem_s;
                unsigned cum = 0;
                for (int bq = nb - 1; bq >= 0; --bq) {
                    unsigned h = hist[bq];
                    if ((int)cum < rem && rem <= (int)(cum + h)) {
                        selb_s = (unsigned)bq;
                        selrem_s = rem - (int)cum;
                        break;
                    }
                    cum += h;
                }
            }
            __syncthreads();
            prefix = (prefix << width) | (unsigned long long)selb_s;
            __syncthreads();
        }
        T = prefix;
    }

    wl[t] = 0ull;
    __syncthreads();
    for (int idx = t; idx < CM1 * MAXDET; idx += 256) {
        int c = idx / MAXDET;
        if (idx - c * MAXDET < kc[c]) {
            unsigned long long key = keys[idx];
            if (key >= T) {
                int s = atomicAdd(&gcnt, 1);
                if (s < 256) wl[s] = key;
            }
        }
    }
    __syncthreads();

    for (int k = 2; k <= 256; k <<= 1) {
        for (int j = k >> 1; j > 0; j >>= 1) {
            int ixj = t ^ j;
            if (ixj > t) {
                unsigned long long u = wl[t], v = wl[ixj];
                bool desc = ((t & k) == 0);
                if (desc ? (u < v) : (u > v)) { wl[t] = v; wl[ixj] = u; }
            }
            __syncthreads();
        }
    }

    if (t < MAXDET) {
        unsigned long long key = wl[t];
        if (key == 0ull) {
            ob[t * 4 + 0] = 0.0f; ob[t * 4 + 1] = 0.0f;
            ob[t * 4 + 2] = 0.0f; ob[t * 4 + 3] = 0.0f;
            os[t] = 0.0f; ol[t] = 0.0f;
        } else {
            int a = (int)(key & 0x3FFFull);
            int flat = 131071 - (int)((key >> 14) & 0x1FFFFull);
            int cmv = flat / TOPK;
            const float* bp = bx + (size_t)a * 4;
            ob[t * 4 + 0] = bp[0]; ob[t * 4 + 1] = bp[1];
            ob[t * 4 + 2] = bp[2]; ob[t * 4 + 3] = bp[3];
            os[t] = __uint_as_float((unsigned)(key >> 31));
            ol[t] = (float)(cmv + 1);
        }
    }
}

// ---------------------------------------------------------------- host launcher
extern "C" void kernel_launch(void* const* d_in, const int* in_sizes, int n_in,
                              void* d_out, int out_size, void* d_ws, size_t ws_size,
                              hipStream_t stream) {
    const void* logits  = d_in[0];   // [32, 8732, 91] f32
    const void* rel     = d_in[1];   // [32, 8732, 4]
    const void* anchors = d_in[2];   // [8732, 4]
    float* out = (float*)d_out;      // boxes|scores|labels flat, f32

    char* ws = (char*)d_ws;
    size_t off = 0;
    auto alloc = [&](size_t bytes) -> void* {
        void* p = ws + off;
        off = (off + bytes + 255) & ~(size_t)255;
        return p;
    };
    float* boxes  = (float*)alloc((size_t)B_N * A_N * 4 * sizeof(float));
    float* amax   = (float*)alloc((size_t)B_N * A_N * sizeof(float));
    float* denom  = (float*)alloc((size_t)B_N * A_N * sizeof(float));
    int*   flag   = (int*)alloc(256);
    unsigned long long* kkey = (unsigned long long*)alloc((size_t)B_N * CM1 * MAXDET * sizeof(unsigned long long));
    int* kcnt     = (int*)alloc((size_t)B_N * CM1 * sizeof(int));

    // transposed masked-SCORE buffer: [B][90][A] u32 — ~96 MiB. Only used if
    // the workspace can hold it; else fall back to the proven path.
    size_t scT_bytes = (size_t)B_N * CM1 * A_N * sizeof(unsigned);
    unsigned* scT = nullptr;
    if (off + scT_bytes <= ws_size) scT = (unsigned*)alloc(scT_bytes);

    int gridBA = (B_N * A_N + 255) / 256;

    k_sniff<<<1, 256, 0, stream>>>((const unsigned*)logits, flag);
    k_stats<<<gridBA, 256, 0, stream>>>(logits, rel, anchors, flag, amax, denom, boxes, scT);
    if (scT)
        k_topknms_pre<<<B_N * CM1, NT, 0, stream>>>(scT, boxes, kkey, kcnt);
    else
        k_topknms<<<B_N * CM1, NT, 0, stream>>>(logits, flag, amax, denom, boxes, kkey, kcnt);
    k_merge<<<B_N, 256, 0, stream>>>(kkey, kcnt, boxes, out);
}

// Round 8
// 693.814 us; speedup vs baseline: 1.0621x; 1.0621x over previous
//
#include <hip/hip_runtime.h>
#include <hip/hip_bf16.h>
#include <cstdint>
#include <cstddef>
#include <math.h>

// Match numpy f32 per-op rounding: no FMA contraction, no reassociation.
// (fmaf() below is explicit and unaffected by the pragma.)
#pragma clang fp contract(off)

#define A_N 8732
#define C_N 91
#define CM1 90
#define B_N 32
#define TOPK 400
#define MAXDET 200
#define NT 512                              /* threads in k_topknms */
#define CCAP 1024                           /* candidate-list capacity */
#define BBOX_CLIPF 4.135166556742356f       /* log(1000/16) cast to f32 */

// Exact predicate constant: for c = 0.45f (even mantissa),
// RN(x/y) > c  <=>  x > (c + 2^-26)*y  with the product exact in double
// (25-bit * 24-bit mantissa). Bit-equivalent to the IEEE f32 divide+compare.
#define IOU_M ((double)0.45f + 0x1p-26)

// 16B vector of floats with only 4B alignment guarantee (rows are 91 floats,
// so row bases are 4B- but not 16B-aligned).
typedef float f4u __attribute__((ext_vector_type(4), aligned(4)));

// Dual-path input load (reference is float32; sniff is insurance).
__device__ __forceinline__ float ldin(const void* p, size_t i, int isbf16) {
    if (isbf16) return __bfloat162float(((const __hip_bfloat16*)p)[i]);
    return ((const float*)p)[i];
}

// numpy SIMD f32 exp — bit-faithful (PROVEN bit-exact, absmax 0.0).
// DO NOT alter any constant or association.
__device__ __forceinline__ float np_expf(float x) {
    float q = rintf(x * 1.442695040f);
    float r = fmaf(q, -0.693359375f, x);
    r = fmaf(q, 2.12194440e-4f, r);
    float p = 1.9875691500E-4f;
    p = fmaf(p, r, 1.3981999507E-3f);
    p = fmaf(p, r, 8.3334519073E-3f);
    p = fmaf(p, r, 4.1665795894E-2f);
    p = fmaf(p, r, 1.6666665459E-1f);
    p = fmaf(p, r, 5.0000001201E-1f);
    p = fmaf(p, r, 1.0f);
    p = fmaf(p, r, 1.0f);
    return ldexpf(p, (int)q);
}

// ---------------------------------------------------------------- dtype sniff (+ done reset)
__global__ void k_sniff(const unsigned* __restrict__ words, int* __restrict__ flag,
                        int* __restrict__ done) {
    __shared__ int cnt_s;
    if (threadIdx.x == 0) cnt_s = 0;
    if (threadIdx.x < B_N) done[threadIdx.x] = 0;   // last-block counters
    __syncthreads();
    int local = 0;
    for (int i = threadIdx.x; i < 4096; i += 256) {
        unsigned w = words[i];
        unsigned e = (w >> 7) & 0xFFu;
        if (e >= 100u && e <= 140u) local++;
    }
    atomicAdd(&cnt_s, local);
    __syncthreads();
    if (threadIdx.x == 0) flag[0] = (cnt_s > 2048) ? 1 : 0;
}

// ---------------------------------------------------------------- softmax + score + decode (fused)
// SINGLE pass over the logits row held in registers. Max chain, np_expf per
// class, exact numpy pairwise r[8] denom, then sc = e/res (identical quotient
// bits to the consumer's old divide) masked with > 0.01f and stored TRANSPOSED
// to scT[(b*90+c-1)*A + a]. amax/denom still written (fallback needs them).
__global__ void k_stats(const void* __restrict__ logits,
                        const void* __restrict__ rel,
                        const void* __restrict__ anchors,
                        const int* __restrict__ flag,
                        float* __restrict__ amax,
                        float* __restrict__ denom,
                        float* __restrict__ boxes,
                        unsigned* __restrict__ scT) {
    int i = blockIdx.x * blockDim.x + threadIdx.x;
    if (i >= B_N * A_N) return;
    int bf = flag[0];
    size_t base = (size_t)i * C_N;
    int bb = i / A_N, aa = i - bb * A_N;
    unsigned* sbase = scT ? (scT + (size_t)bb * CM1 * A_N + aa) : (unsigned*)0;

    if (!bf) {
        const float* lp = (const float*)logits + base;
        float x[91];
        #pragma unroll
        for (int k = 0; k < 22; ++k) {
            f4u v = *(const f4u*)(lp + 4 * k);
            x[4 * k + 0] = v.x; x[4 * k + 1] = v.y;
            x[4 * k + 2] = v.z; x[4 * k + 3] = v.w;
        }
        x[88] = lp[88]; x[89] = lp[89]; x[90] = lp[90];

        float m = -INFINITY;
        #pragma unroll
        for (int c = 0; c < 91; ++c) m = fmaxf(m, x[c]);

        #pragma unroll
        for (int c = 0; c < 91; ++c) x[c] = np_expf(x[c] - m);   // x := e

        // exact numpy pairwise: r[j] = sum_k e[8k+j], k ascending (as before)
        float r[8];
        #pragma unroll
        for (int j = 0; j < 8; ++j) {
            float s = x[j];
            #pragma unroll
            for (int k = 1; k < 11; ++k) s += x[8 * k + j];
            r[j] = s;
        }
        float res = ((r[0] + r[1]) + (r[2] + r[3])) + ((r[4] + r[5]) + (r[6] + r[7]));
        res += x[88]; res += x[89]; res += x[90];
        amax[i]  = m;
        denom[i] = res;

        if (sbase) {
            #pragma unroll
            for (int c = 1; c < 91; ++c) {
                float sc = x[c] / res;       // identical quotient bits to the
                                             // consumer's old e/denom divide
                sbase[(size_t)(c - 1) * A_N] =
                    (sc > 0.01f) ? __float_as_uint(sc) : 0u;
            }
        }
    } else {
        // bf16 insurance path — scalar, same proven structure; emits sc bits.
        float m = -INFINITY;
        for (int c = 0; c < C_N; ++c) m = fmaxf(m, ldin(logits, base + c, bf));
        float r[8];
        for (int j = 0; j < 8; ++j) r[j] = np_expf(ldin(logits, base + j, bf) - m);
        for (int c = 8; c < 88; c += 8)
            for (int j = 0; j < 8; ++j) r[j] += np_expf(ldin(logits, base + c + j, bf) - m);
        float res = ((r[0] + r[1]) + (r[2] + r[3])) + ((r[4] + r[5]) + (r[6] + r[7]));
        res += np_expf(ldin(logits, base + 88, bf) - m);
        res += np_expf(ldin(logits, base + 89, bf) - m);
        res += np_expf(ldin(logits, base + 90, bf) - m);
        amax[i]  = m;
        denom[i] = res;
        if (sbase) {
            for (int c = 1; c < C_N; ++c) {
                float sc = np_expf(ldin(logits, base + c, bf) - m) / res;
                sbase[(size_t)(c - 1) * A_N] =
                    (sc > 0.01f) ? __float_as_uint(sc) : 0u;
            }
        }
    }

    // ---- fused box decode (PROVEN bit-exact expressions) ----
    {
        int a = aa;
        float ax1, ay1, ax2, ay2, r0, r1, r2, r3;
        if (!bf) {
            float4 av = ((const float4*)anchors)[a];
            float4 rv = ((const float4*)rel)[i];
            ax1 = av.x; ay1 = av.y; ax2 = av.z; ay2 = av.w;
            r0 = rv.x; r1 = rv.y; r2 = rv.z; r3 = rv.w;
        } else {
            ax1 = ldin(anchors, (size_t)a * 4 + 0, bf);
            ay1 = ldin(anchors, (size_t)a * 4 + 1, bf);
            ax2 = ldin(anchors, (size_t)a * 4 + 2, bf);
            ay2 = ldin(anchors, (size_t)a * 4 + 3, bf);
            r0 = ldin(rel, (size_t)i * 4 + 0, bf);
            r1 = ldin(rel, (size_t)i * 4 + 1, bf);
            r2 = ldin(rel, (size_t)i * 4 + 2, bf);
            r3 = ldin(rel, (size_t)i * 4 + 3, bf);
        }
        float wa = ax2 - ax1, ha = ay2 - ay1;
        float cxa = ax1 + 0.5f * wa, cya = ay1 + 0.5f * ha;
        float dx = r0 / 10.0f, dy = r1 / 10.0f;
        float dw = fminf(r2 / 5.0f, BBOX_CLIPF);
        float dh = fminf(r3 / 5.0f, BBOX_CLIPF);
        float cx = dx * wa + cxa, cy = dy * ha + cya;
        float w = np_expf(dw) * wa, h = np_expf(dh) * ha;
        float4 o;
        o.x = fminf(fmaxf(cx - 0.5f * w, 0.0f), 300.0f);
        o.y = fminf(fmaxf(cy - 0.5f * h, 0.0f), 300.0f);
        o.z = fminf(fmaxf(cx + 0.5f * w, 0.0f), 300.0f);
        o.w = fminf(fmaxf(cy + 0.5f * h, 0.0f), 300.0f);
        ((float4*)boxes)[i] = o;
    }
}

// ---------------------------------------------------------------- fused top-400 + NMS + last-block merge
// v9: r6's PROVEN on-demand ballot NMS restored (r7's build+scan split
// regressed — 2x wave-0 critical section). Select keeps the r7 fast path.
// After emission, the last class-block of each image (device atomic counter)
// runs the per-image top-200 merge in-block — removes the k_merge dispatch.
__global__ __launch_bounds__(NT) void k_topknms_pre(const unsigned* __restrict__ scT,
                                                    const float* __restrict__ boxes,
                                                    unsigned long long* __restrict__ kkey,
                                                    int* __restrict__ kcnt,
                                                    float* __restrict__ out,
                                                    int* __restrict__ done) {
    __shared__ __align__(16) float4 nbq[TOPK];      // 6400 B
    __shared__ float sar[TOPK];                     // 1600 B
    __shared__ unsigned long long wlist[512];       // 4096 B
    __shared__ unsigned long long cand[CCAP];       // 8192 B
    __shared__ unsigned hist[1024];                 // 4096 B
    __shared__ unsigned long long fsup[8];
    __shared__ unsigned long long ksv[8];
    __shared__ unsigned sel_b;
    __shared__ int sel_rem;
    __shared__ int nreal_s;
    __shared__ int eqlist[64];
    __shared__ int eqn, nsel, candn, total_s, islast_s;

    int bc = blockIdx.x;
    int b  = bc / CM1;
    int cm = bc % CM1;                       // class row 0..89 (logit col cm+1)
    int t  = threadIdx.x;

    const unsigned* srow = scT + (size_t)bc * A_N;
    const uint4* srow4 = (const uint4*)srow;

    // ---- phase 0: stream masked score bits, build level-1 histogram.
    if (t == 0) { eqn = 0; nsel = 0; candn = 0; total_s = 0; }
    for (int q = t; q < 1024; q += NT) hist[q] = 0u;
    __syncthreads();
    for (int k = t; k < A_N / 4; k += NT) {
        uint4 v = srow4[k];
        if (v.x) atomicAdd(&hist[(v.x >> 16) & 0x3FFu], 1u);
        if (v.y) atomicAdd(&hist[(v.y >> 16) & 0x3FFu], 1u);
        if (v.z) atomicAdd(&hist[(v.z >> 16) & 0x3FFu], 1u);
        if (v.w) atomicAdd(&hist[(v.w >> 16) & 0x3FFu], 1u);
    }
    __syncthreads();

    // ---- level-1 scan: suffix sums give BOTH nreal and the 400th bucket.
    if (t < 64) {
        unsigned s = 0;
        #pragma unroll
        for (int q = 0; q < 16; ++q) s += hist[16 * t + q];
        unsigned suf = s;
        for (int o = 1; o < 64; o <<= 1) {
            unsigned vv = __shfl_down(suf, o);
            if (t + o < 64) suf += vv;
        }
        if (t == 0) nreal_s = (int)suf;
        unsigned cum = suf - s;
        for (int q = 15; q >= 0; --q) {
            unsigned h = hist[16 * t + q];
            if ((int)cum < TOPK && TOPK <= (int)(cum + h)) {
                sel_b = (unsigned)(16 * t + q);
                sel_rem = TOPK - (int)cum;
            }
            cum += h;
        }
    }
    __syncthreads();
    int nreal = nreal_s;
    bool sel_path = (nreal >= TOPK);         // block-uniform
    unsigned selL1 = sel_b;                  // valid iff sel_path
    unsigned prefix1 = (0xFu << 10) | selL1;
    __syncthreads();

    // ---- pass B: classify. bucket>selL1 -> wlist; bucket==selL1 -> cand
    // (+ level-2 histogram for the slow path); !sel_path: all nonzero -> wlist.
    if (sel_path) { for (int q = t; q < 1024; q += NT) hist[q] = 0u; }
    __syncthreads();
    for (int k = t; k < A_N / 4; k += NT) {
        uint4 vv = srow4[k];
        unsigned va[4] = {vv.x, vv.y, vv.z, vv.w};
        #pragma unroll
        for (int c = 0; c < 4; ++c) {
            unsigned v = va[c];
            if (!v) continue;
            unsigned a = (unsigned)(4 * k + c);
            if (sel_path) {
                unsigned bkt = (v >> 16) & 0x3FFu;
                if (bkt > selL1) {
                    int slot = atomicAdd(&nsel, 1);
                    if (slot < 512)
                        wlist[slot] = ((unsigned long long)v << 32) | (unsigned)(~a);
                } else if (bkt == selL1) {
                    int s2 = atomicAdd(&candn, 1);
                    if (s2 < CCAP)
                        cand[s2] = ((unsigned long long)v << 32) | (unsigned)(~a);
                    atomicAdd(&hist[(v >> 6) & 0x3FFu], 1u);
                }
            } else {
                int slot = atomicAdd(&nsel, 1);
                if (slot < 512)
                    wlist[slot] = ((unsigned long long)v << 32) | (unsigned)(~a);
            }
        }
    }
    __syncthreads();

    if (sel_path) {
        int ngt = nsel;                      // strictly-greater count (<400)
        int cn  = candn;                     // boundary-bucket count
        bool fast = (cn <= CCAP) && (ngt + cn <= 512);
        if (fast) {
            // exact: sort of (gt ∪ bucket) desc by (score, anchor asc) and
            // truncation to 400 == proven selection + tie rule.
            for (int q = t; q < cn; q += NT) wlist[ngt + q] = cand[q];
            __syncthreads();
            if (t == 0) nsel = ngt + cn;
            __syncthreads();
        } else {
            // ---- slow path (verbatim proven logic) ----
            bool ovf = (cn > CCAP);
            if (t < 64) {
                int rem = sel_rem;
                unsigned s = 0;
                #pragma unroll
                for (int q = 0; q < 16; ++q) s += hist[16 * t + q];
                unsigned suf = s;
                for (int o = 1; o < 64; o <<= 1) {
                    unsigned vv = __shfl_down(suf, o);
                    if (t + o < 64) suf += vv;
                }
                unsigned cum = suf - s;
                for (int q = 15; q >= 0; --q) {
                    unsigned h = hist[16 * t + q];
                    if ((int)cum < rem && rem <= (int)(cum + h)) {
                        sel_b = (unsigned)(16 * t + q);
                        sel_rem = rem - (int)cum;
                    }
                    cum += h;
                }
            }
            __syncthreads();
            unsigned prefix2 = (prefix1 << 10) | sel_b;

            if (t < 64) hist[t] = 0u;
            __syncthreads();
            if (!ovf) {
                int cc = cn < CCAP ? cn : CCAP;
                for (int q = t; q < cc; q += NT) {
                    unsigned v = (unsigned)(cand[q] >> 32);
                    if ((v >> 6) == prefix2) atomicAdd(&hist[v & 0x3Fu], 1u);
                }
            } else {
                for (int a = t; a < A_N; a += NT) {
                    unsigned v = srow[a];
                    if (v && (v >> 6) == prefix2) atomicAdd(&hist[v & 0x3Fu], 1u);
                }
            }
            __syncthreads();
            if (t == 0) {
                int rem = sel_rem;
                unsigned cum = 0;
                for (int bq = 63; bq >= 0; --bq) {
                    unsigned h = hist[bq];
                    if ((int)cum < rem && rem <= (int)(cum + h)) {
                        sel_b = (unsigned)bq;
                        sel_rem = rem - (int)cum;
                        break;
                    }
                    cum += h;
                }
            }
            __syncthreads();
            unsigned sstar = (prefix2 << 6) | sel_b;
            int teq = sel_rem;

            if (!ovf) {
                int cc = cn < CCAP ? cn : CCAP;
                for (int q = t; q < cc; q += NT) {
                    unsigned long long cv = cand[q];
                    unsigned v = (unsigned)(cv >> 32);
                    if (v > sstar) {
                        int slot = atomicAdd(&nsel, 1);
                        if (slot < 512) wlist[slot] = cv;
                    } else if (v == sstar) {
                        int s2 = atomicAdd(&eqn, 1);
                        if (s2 < 64) eqlist[s2] = (int)(~(unsigned)cv);
                    }
                }
            } else {
                for (int a = t; a < A_N; a += NT) {
                    unsigned v = srow[a];
                    if (!v) continue;
                    if ((v >> 16) == prefix1) {
                        if (v > sstar) {
                            int slot = atomicAdd(&nsel, 1);
                            if (slot < 512)
                                wlist[slot] = ((unsigned long long)v << 32) |
                                              (unsigned)(~(unsigned)a);
                        } else if (v == sstar) {
                            int s2 = atomicAdd(&eqn, 1);
                            if (s2 < 64) eqlist[s2] = a;
                        }
                    }
                }
            }
            __syncthreads();
            if (t == 0) {
                int n = eqn < 64 ? eqn : 64; // same 64-cap as proven kernel
                for (int i2 = 1; i2 < n; ++i2) {
                    int v2 = eqlist[i2], j2 = i2 - 1;
                    while (j2 >= 0 && eqlist[j2] > v2) { eqlist[j2 + 1] = eqlist[j2]; --j2; }
                    eqlist[j2 + 1] = v2;
                }
                int tq = teq < n ? teq : n;
                int bse = nsel;
                for (int q2 = 0; q2 < tq; ++q2) {
                    int slot = bse + q2;
                    if (slot < 512)
                        wlist[slot] = ((unsigned long long)sstar << 32) |
                                      (unsigned)(~(unsigned)eqlist[q2]);
                }
                nsel = bse + tq;
            }
            __syncthreads();
        }
    }
    int ns = nsel < 512 ? nsel : 512;
    if (t >= ns) wlist[t] = 0ull;
    __syncthreads();

    // ---- bitonic sort 512 desc, register-resident; shfl_xor for j<=32,
    // LDS exchange only for j>=64. Same network => identical permutation.
    {
        unsigned long long u = wlist[t];
        for (int k = 2; k <= 512; k <<= 1) {
            bool up = ((t & k) == 0);
            for (int j = k >> 1; j >= 64; j >>= 1) {
                __syncthreads();
                wlist[t] = u;
                __syncthreads();
                unsigned long long v = wlist[t ^ j];
                bool takeMax = (((t & j) == 0) == up);
                u = takeMax ? (u > v ? u : v) : (u < v ? u : v);
            }
            for (int j = ((k >> 1) < 64 ? (k >> 1) : 32); j > 0; j >>= 1) {
                unsigned long long v = __shfl_xor(u, j);
                bool takeMax = (((t & j) == 0) == up);
                u = takeMax ? (u > v ? u : v) : (u < v ? u : v);
            }
        }
        __syncthreads();
        wlist[t] = u;
        __syncthreads();
    }

    // ---- per-class NMS on the sorted top-400: r6's PROVEN on-demand form ----
    int m = ns < TOPK ? ns : TOPK;
    float offc = (float)(cm + 1) * 301.0f;
    if (t < m) {
        unsigned aidx = ~(unsigned)(wlist[t] & 0xFFFFFFFFull);
        const float* bp = boxes + ((size_t)b * A_N + aidx) * 4;
        float4 q;
        q.x = bp[0] + offc; q.y = bp[1] + offc;   // same exprs as proven code
        q.z = bp[2] + offc; q.w = bp[3] + offc;
        nbq[t] = q;
        sar[t] = (q.z - q.x) * (q.w - q.y);       // == bar[t] bits
    }
    if (t < 8) { fsup[t] = 0ull; ksv[t] = 0ull; }
    __syncthreads();

    int nch = (m + 63) >> 6;
    for (int g = 0; g < nch; ++g) {
        // wave 0: greedy scan of chunk g; masks of kept rows built on the
        // fly via ballot (lane = column within chunk). Decisions identical
        // to the proven serial scan.
        if (t < 64) {
            int bse = 64 * g;
            int jmax = m - bse; if (jmax > 64) jmax = 64;
            bool valid = t < jmax;
            float4 cb = valid ? nbq[bse + t] : make_float4(0.f, 0.f, 0.f, 0.f);
            float car = valid ? sar[bse + t] : 0.0f;
            unsigned long long sup = fsup[g], kv = 0ull;
            unsigned long long rem =
                ((jmax == 64) ? ~0ull : ((1ull << jmax) - 1ull)) & ~sup;
            while (rem) {
                int j = __builtin_ctzll(rem);    // next non-suppressed row
                float rx1 = __shfl(cb.x, j), ry1 = __shfl(cb.y, j);
                float rx2 = __shfl(cb.z, j), ry2 = __shfl(cb.w, j);
                float ra  = __shfl(car, j);
                bool p = false;
                if (valid && t > j) {            // strictly j<col, like j>i2
                    float lx = fmaxf(rx1, cb.x), ly = fmaxf(ry1, cb.y);
                    float rx = fminf(rx2, cb.z), ry = fminf(ry2, cb.w);
                    float ww = fmaxf(rx - lx, 0.0f), hh = fmaxf(ry - ly, 0.0f);
                    float inter = ww * hh;
                    float U = ra + car - inter + 1e-9f;   // row area first
                    p = ((double)inter > IOU_M * (double)U);
                }
                unsigned long long wj = __ballot(p);
                kv |= 1ull << j;
                sup |= wj;
                rem &= ~(sup | (1ull << j));
            }
            if (t == 0) { ksv[g] = kv; total_s += __popcll(kv); }
        }
        __syncthreads();
        if (total_s >= MAXDET) break;        // uniform; rows past the 200th
                                             // kept are never emitted anyway
        if (g + 1 < nch) {
            // waves 1..: future-word suppression = OR over kept rows of
            // chunk g (broadcast LDS reads; lane = column of word h).
            int w = t >> 6, l = t & 63;
            int h = g + 1 + w;
            if (h < nch) {
                unsigned long long kv = ksv[g];
                int jmax2 = m - 64 * h; if (jmax2 > 64) jmax2 = 64;
                bool v2 = l < jmax2;
                float4 cbl = v2 ? nbq[64 * h + l] : make_float4(0.f, 0.f, 0.f, 0.f);
                float cal = v2 ? sar[64 * h + l] : 0.0f;
                bool acc = false;
                unsigned long long rr = kv;
                while (rr) {
                    int r = __builtin_ctzll(rr); rr &= rr - 1;
                    float4 rq = nbq[64 * g + r];     // wave-uniform broadcast
                    float rar = sar[64 * g + r];
                    if (v2 && !acc) {
                        float lx = fmaxf(rq.x, cbl.x), ly = fmaxf(rq.y, cbl.y);
                        float rx = fminf(rq.z, cbl.z), ry = fminf(rq.w, cbl.w);
                        float ww = fmaxf(rx - lx, 0.0f), hh = fmaxf(ry - ly, 0.0f);
                        float inter = ww * hh;
                        float U = rar + cal - inter + 1e-9f;
                        acc = ((double)inter > IOU_M * (double)U);
                    }
                }
                unsigned long long wd = __ballot(acc);
                if (l == 0) fsup[h] |= wd;
            }
        }
        __syncthreads();
    }

    // rank-parallel emission (kept order == row order == serial order)
    if (t < 64) {
        int l = t, basek = 0;
        for (int g = 0; g < nch; ++g) {
            unsigned long long kv = ksv[g];
            int row = 64 * g + l;
            if ((kv >> l) & 1ull) {
                int rank = basek + __popcll(kv & ((1ull << l) - 1ull));
                if (rank < MAXDET) {
                    unsigned long long wv = wlist[row];
                    unsigned sbts = (unsigned)(wv >> 32);
                    unsigned aa2  = ~(unsigned)wv;        // anchor, <16384
                    int flat = cm * TOPK + row;
                    unsigned long long key =
                        ((unsigned long long)sbts << 31) |
                        ((unsigned long long)(131071 - flat) << 14) |
                        (unsigned long long)aa2;
                    kkey[(size_t)bc * MAXDET + rank] = key;
                }
            }
            basek += __popcll(kv);
        }
        if (l == 0) kcnt[bc] = total_s < MAXDET ? total_s : MAXDET;
    }

    // ---- last-block-per-image fused merge (canonical threadfence pattern) ----
    __syncthreads();
    if (t == 0) {
        __threadfence();                        // publish kkey/kcnt
        int prev = atomicAdd(&done[b], 1);      // device-scope by default
        islast_s = (prev == CM1 - 1);
    }
    __syncthreads();
    if (!islast_s) return;
    __threadfence();                            // see other blocks' writes

    {
        unsigned long long* wl = cand;          // [0..255]
        int* kc = (int*)(cand + 512);           // 90 ints (disjoint from wl)
        const unsigned long long* keys = kkey + (size_t)b * (CM1 * MAXDET);
        const float* bx = boxes + (size_t)b * A_N * 4;
        float* ob = out + (size_t)b * MAXDET * 4;
        float* os = out + (size_t)B_N * MAXDET * 4 + (size_t)b * MAXDET;
        float* ol = out + (size_t)B_N * MAXDET * 5 + (size_t)b * MAXDET;

        if (t < CM1) kc[t] = kcnt[b * CM1 + t];
        if (t == 0) { total_s = 0; nsel = 0; sel_rem = MAXDET; }
        __syncthreads();

        {   // total kept across 90 classes
            int c0 = 0;
            for (int idx = t; idx < CM1 * MAXDET; idx += NT) {
                int c = idx / MAXDET;
                if (idx - c * MAXDET < kc[c]) c0++;
            }
            for (int o = 32; o; o >>= 1) c0 += __shfl_down(c0, o);
            if ((t & 63) == 0) atomicAdd(&total_s, c0);
        }
        __syncthreads();
        int total = total_s;

        unsigned long long T = 0ull;            // take keys >= T
        if (total > MAXDET) {
            unsigned long long prefix = 0ull;
            for (int l = 0; l < 7; ++l) {
                int width = (l == 6) ? 2 : 10;
                int shift = (l == 6) ? 0 : (52 - 10 * l);
                int nb = 1 << width;
                for (int q = t; q < nb; q += NT) hist[q] = 0u;
                __syncthreads();
                for (int idx = t; idx < CM1 * MAXDET; idx += NT) {
                    int c = idx / MAXDET;
                    if (idx - c * MAXDET < kc[c]) {
                        unsigned long long key = keys[idx];
                        if ((key >> (shift + width)) == prefix)
                            atomicAdd(&hist[(unsigned)(key >> shift) & (unsigned)(nb - 1)], 1u);
                    }
                }
                __syncthreads();
                if (nb >= 64) {
                    if (t < 64) {
                        int rem = sel_rem;
                        int per = nb / 64;
                        unsigned s = 0;
                        for (int q = 0; q < per; ++q) s += hist[per * t + q];
                        unsigned suf = s;
                        for (int o = 1; o < 64; o <<= 1) {
                            unsigned vv = __shfl_down(suf, o);
                            if (t + o < 64) suf += vv;
                        }
                        unsigned cum = suf - s;
                        for (int q = per - 1; q >= 0; --q) {
                            unsigned h = hist[per * t + q];
                            if ((int)cum < rem && rem <= (int)(cum + h)) {
                                sel_b = (unsigned)(per * t + q);
                                sel_rem = rem - (int)cum;
                            }
                            cum += h;
                        }
                    }
                } else if (t == 0) {
                    int rem = sel_rem;
                    unsigned cum = 0;
                    for (int bq = nb - 1; bq >= 0; --bq) {
                        unsigned h = hist[bq];
                        if ((int)cum < rem && rem <= (int)(cum + h)) {
                            sel_b = (unsigned)bq;
                            sel_rem = rem - (int)cum;
                            break;
                        }
                        cum += h;
                    }
                }
                __syncthreads();
                prefix = (prefix << width) | (unsigned long long)sel_b;
                __syncthreads();
            }
            T = prefix;                         // exact 200th-largest key
        }

        if (t < 256) wl[t] = 0ull;
        __syncthreads();
        for (int idx = t; idx < CM1 * MAXDET; idx += NT) {
            int c = idx / MAXDET;
            if (idx - c * MAXDET < kc[c]) {
                unsigned long long key = keys[idx];
                if (key >= T) {
                    int s = atomicAdd(&nsel, 1);
                    if (s < 256) wl[s] = key;
                }
            }
        }
        __syncthreads();

        // bitonic sort 256 desc in LDS (all threads hit the barriers)
        for (int k2 = 2; k2 <= 256; k2 <<= 1) {
            for (int j = k2 >> 1; j > 0; j >>= 1) {
                if (t < 256) {
                    int ixj = t ^ j;
                    if (ixj > t) {
                        unsigned long long u = wl[t], v = wl[ixj];
                        bool desc = ((t & k2) == 0);
                        if (desc ? (u < v) : (u > v)) { wl[t] = v; wl[ixj] = u; }
                    }
                }
                __syncthreads();
            }
        }

        if (t < MAXDET) {
            unsigned long long key = wl[t];
            if (key == 0ull) {
                ob[t * 4 + 0] = 0.0f; ob[t * 4 + 1] = 0.0f;
                ob[t * 4 + 2] = 0.0f; ob[t * 4 + 3] = 0.0f;
                os[t] = 0.0f; ol[t] = 0.0f;
            } else {
                int a = (int)(key & 0x3FFFull);
                int flat = 131071 - (int)((key >> 14) & 0x1FFFFull);
                int cmv = flat / TOPK;
                const float* bp = bx + (size_t)a * 4;
                ob[t * 4 + 0] = bp[0]; ob[t * 4 + 1] = bp[1];
                ob[t * 4 + 2] = bp[2]; ob[t * 4 + 3] = bp[3];
                os[t] = __uint_as_float((unsigned)(key >> 31));
                ol[t] = (float)(cmv + 1);
            }
        }
    }
}

// ---------------------------------------------------------------- FALLBACK top-400 + NMS
// Verbatim proven kernel (used only if the workspace can't hold scT).
__global__ __launch_bounds__(NT) void k_topknms(const void* __restrict__ logits,
                                                const int* __restrict__ flag,
                                                const float* __restrict__ amax,
                                                const float* __restrict__ denom,
                                                const float* __restrict__ boxes,
                                                unsigned long long* __restrict__ kkey,
                                                int* __restrict__ kcnt) {
    __shared__ union {
        unsigned sbits[A_N];
        unsigned long long msk[TOPK * 7];
    } su;
    __shared__ unsigned long long wlist[512];
    __shared__ float bx1[TOPK], by1[TOPK], bx2[TOPK], by2[TOPK], bar[TOPK];
    __shared__ int wred[NT / 64];
    __shared__ unsigned bcast_p;
    __shared__ int bcast_rem;
    __shared__ int eqlist[64];
    __shared__ int eqn;
    __shared__ int bcast_athr;
    __shared__ int nsel;

    int bc = blockIdx.x;
    int b  = bc / CM1;
    int cm = bc % CM1;
    int bf = flag[0];
    int t  = threadIdx.x;

    for (int a = t; a < A_N; a += NT) {
        size_t base = (size_t)b * A_N + a;
        float e  = np_expf(ldin(logits, base * C_N + (cm + 1), bf) - amax[base]);
        float sc = e / denom[base];
        su.sbits[a] = (sc > 0.01f) ? __float_as_uint(sc) : 0u;
    }
    if (t == 0) { eqn = 0; nsel = 0; }
    __syncthreads();

    {
        int c0 = 0;
        for (int a = t; a < A_N; a += NT) c0 += (su.sbits[a] != 0u);
        for (int o = 32; o; o >>= 1) c0 += __shfl_down(c0, o);
        if ((t & 63) == 0) wred[t >> 6] = c0;
        __syncthreads();
        if (t == 0) {
            int tot = 0;
            for (int wv = 0; wv < NT / 64; ++wv) tot += wred[wv];
            bcast_rem = tot;
        }
        __syncthreads();
    }
    int nreal = bcast_rem;
    __syncthreads();

    unsigned sstar = 0u;
    int teq = 0;
    if (nreal >= TOPK) {
        unsigned p = 0x3C000000u;
        int rem = TOPK;
        for (int bit = 25; bit >= 0; --bit) {
            unsigned q = p | (1u << bit);
            int cnt = 0;
            for (int a = t; a < A_N; a += NT) cnt += ((su.sbits[a] >> bit) == (q >> bit));
            for (int o = 32; o; o >>= 1) cnt += __shfl_down(cnt, o);
            if ((t & 63) == 0) wred[t >> 6] = cnt;
            __syncthreads();
            if (t == 0) {
                int tot = 0;
                for (int wv = 0; wv < NT / 64; ++wv) tot += wred[wv];
                if (tot >= rem) { bcast_p = q; bcast_rem = rem; }
                else            { bcast_p = p; bcast_rem = rem - tot; }
            }
            __syncthreads();
            p = bcast_p; rem = bcast_rem;
            __syncthreads();
        }
        sstar = p;
        teq = rem;
        for (int a = t; a < A_N; a += NT) {
            if (su.sbits[a] == sstar) {
                int slot = atomicAdd(&eqn, 1);
                if (slot < 64) eqlist[slot] = a;
            }
        }
        __syncthreads();
        if (t == 0) {
            int n = eqn < 64 ? eqn : 64;
            for (int i = 1; i < n; ++i) {
                int v = eqlist[i], j = i - 1;
                while (j >= 0 && eqlist[j] > v) { eqlist[j + 1] = eqlist[j]; --j; }
                eqlist[j + 1] = v;
            }
            int tq = teq < n ? teq : n;
            bcast_athr = (tq > 0) ? eqlist[tq - 1] : -1;
        }
        __syncthreads();
    }
    int athr = (nreal >= TOPK) ? bcast_athr : -1;
    __syncthreads();

    for (int a = t; a < A_N; a += NT) {
        unsigned v = su.sbits[a];
        bool sel;
        if (nreal >= TOPK)
            sel = (v > sstar) || (v == sstar && a <= athr);
        else
            sel = (v != 0u);
        if (sel) {
            int slot = atomicAdd(&nsel, 1);
            if (slot < 512)
                wlist[slot] = ((unsigned long long)v << 32) | (unsigned)(~(unsigned)a);
        }
    }
    __syncthreads();
    int ns = nsel < 512 ? nsel : 512;
    if (t < 512 && t >= ns) wlist[t] = 0ull;
    __syncthreads();

    for (int k = 2; k <= 512; k <<= 1) {
        for (int j = k >> 1; j > 0; j >>= 1) {
            int ixj = t ^ j;
            if (ixj > t) {
                unsigned long long u = wlist[t], v = wlist[ixj];
                bool desc = ((t & k) == 0);
                if (desc ? (u < v) : (u > v)) { wlist[t] = v; wlist[ixj] = u; }
            }
            __syncthreads();
        }
    }

    int m = ns < TOPK ? ns : TOPK;
    float offc = (float)(cm + 1) * 301.0f;
    if (t < m) {
        unsigned aidx = ~(unsigned)(wlist[t] & 0xFFFFFFFFull);
        const float* bp = boxes + ((size_t)b * A_N + aidx) * 4;
        float x1 = bp[0] + offc, y1 = bp[1] + offc;
        float x2 = bp[2] + offc, y2 = bp[3] + offc;
        bx1[t] = x1; by1[t] = y1; bx2[t] = x2; by2[t] = y2;
        bar[t] = (x2 - x1) * (y2 - y1);
    }
    __syncthreads();

    if (t < m) {
        unsigned long long w[7] = {0, 0, 0, 0, 0, 0, 0};
        float x1 = bx1[t], y1 = by1[t], x2 = bx2[t], y2 = by2[t], a1 = bar[t];
        for (int j = t + 1; j < m; ++j) {
            float lx = fmaxf(x1, bx1[j]), ly = fmaxf(y1, by1[j]);
            float rx = fminf(x2, bx2[j]), ry = fminf(y2, by2[j]);
            float ww = fmaxf(rx - lx, 0.0f), hh = fmaxf(ry - ly, 0.0f);
            float inter = ww * hh;
            float iou = inter / (a1 + bar[j] - inter + 1e-9f);
            if (iou > 0.45f) w[j >> 6] |= 1ull << (j & 63);
        }
        for (int k2 = 0; k2 < 7; ++k2) su.msk[t * 7 + k2] = w[k2];
    }
    __syncthreads();

    if (t == 0) {
        unsigned long long sup[7] = {0, 0, 0, 0, 0, 0, 0};
        int cnt = 0;
        for (int i = 0; i < m; ++i) {
            if (!((sup[i >> 6] >> (i & 63)) & 1ull)) {
                unsigned long long wv = wlist[i];
                unsigned sb2 = (unsigned)(wv >> 32);
                unsigned a  = ~(unsigned)wv;
                int flat = cm * TOPK + i;
                unsigned long long key =
                    ((unsigned long long)sb2 << 31) |
                    ((unsigned long long)(131071 - flat) << 14) |
                    (unsigned long long)a;
                kkey[(size_t)bc * MAXDET + cnt] = key;
                cnt++;
                if (cnt == MAXDET) break;
                const unsigned long long* r = &su.msk[i * 7];
                for (int k2 = 0; k2 < 7; ++k2) sup[k2] |= r[k2];
            }
        }
        kcnt[bc] = cnt;
    }
}

// ---------------------------------------------------------------- parallel per-image top-200
// (fallback path only — the fast path fuses this into k_topknms_pre)
__global__ __launch_bounds__(256) void k_merge(const unsigned long long* __restrict__ kkey,
                                               const int* __restrict__ kcnt,
                                               const float* __restrict__ boxes,
                                               float* __restrict__ out) {
    __shared__ unsigned hist[1024];
    __shared__ unsigned long long wl[256];
    __shared__ int kc[CM1];
    __shared__ int tot_s;
    __shared__ unsigned selb_s;
    __shared__ int selrem_s;
    __shared__ int gcnt;

    int b = blockIdx.x;
    int t = threadIdx.x;
    const unsigned long long* keys = kkey + (size_t)b * (CM1 * MAXDET);
    const float* bx = boxes + (size_t)b * A_N * 4;
    float* ob = out + (size_t)b * MAXDET * 4;
    float* os = out + (size_t)B_N * MAXDET * 4 + (size_t)b * MAXDET;
    float* ol = out + (size_t)B_N * MAXDET * 5 + (size_t)b * MAXDET;

    if (t < CM1) kc[t] = kcnt[b * CM1 + t];
    if (t == 0) { tot_s = 0; gcnt = 0; }
    __syncthreads();

    {
        int c0 = 0;
        for (int idx = t; idx < CM1 * MAXDET; idx += 256) {
            int c = idx / MAXDET;
            if (idx - c * MAXDET < kc[c]) c0++;
        }
        for (int o = 32; o; o >>= 1) c0 += __shfl_down(c0, o);
        if ((t & 63) == 0) atomicAdd(&tot_s, c0);
    }
    __syncthreads();
    int total = tot_s;

    unsigned long long T = 0ull;
    if (total > MAXDET) {
        unsigned long long prefix = 0ull;
        if (t == 0) selrem_s = MAXDET;
        __syncthreads();
        for (int l = 0; l < 7; ++l) {
            int width = (l == 6) ? 2 : 10;
            int shift = (l == 6) ? 0 : (52 - 10 * l);
            int nb = 1 << width;
            for (int q = t; q < nb; q += 256) hist[q] = 0u;
            __syncthreads();
            for (int idx = t; idx < CM1 * MAXDET; idx += 256) {
                int c = idx / MAXDET;
                if (idx - c * MAXDET < kc[c]) {
                    unsigned long long key = keys[idx];
                    if ((key >> (shift + width)) == prefix)
                        atomicAdd(&hist[(unsigned)(key >> shift) & (unsigned)(nb - 1)], 1u);
                }
            }
            __syncthreads();
            if (nb >= 64) {
                if (t < 64) {
                    int rem = selrem_s;
                    int per = nb / 64;
                    unsigned s = 0;
                    for (int q = 0; q < per; ++q) s += hist[per * t + q];
                    unsigned suf = s;
                    for (int o = 1; o < 64; o <<= 1) {
                        unsigned vv = __shfl_down(suf, o);
                        if (t + o < 64) suf += vv;
                    }
                    unsigned cum = suf - s;
                    for (int q = per - 1; q >= 0; --q) {
                        unsigned h = hist[per * t + q];
                        if ((int)cum < rem && rem <= (int)(cum + h)) {
                            selb_s = (unsigned)(per * t + q);
                            selrem_s = rem - (int)cum;
                        }
                        cum += h;
                    }
                }
            } else if (t == 0) {
                int rem = selrem_s;
                unsigned cum = 0;
                for (int bq = nb - 1; bq >= 0; --bq) {
                    unsigned h = hist[bq];
                    if ((int)cum < rem && rem <= (int)(cum + h)) {
                        selb_s = (unsigned)bq;
                        selrem_s = rem - (int)cum;
                        break;
                    }
                    cum += h;
                }
            }
            __syncthreads();
            prefix = (prefix << width) | (unsigned long long)selb_s;
            __syncthreads();
        }
        T = prefix;
    }

    wl[t] = 0ull;
    __syncthreads();
    for (int idx = t; idx < CM1 * MAXDET; idx += 256) {
        int c = idx / MAXDET;
        if (idx - c * MAXDET < kc[c]) {
            unsigned long long key = keys[idx];
            if (key >= T) {
                int s = atomicAdd(&gcnt, 1);
                if (s < 256) wl[s] = key;
            }
        }
    }
    __syncthreads();

    for (int k = 2; k <= 256; k <<= 1) {
        for (int j = k >> 1; j > 0; j >>= 1) {
            int ixj = t ^ j;
            if (ixj > t) {
                unsigned long long u = wl[t], v = wl[ixj];
                bool desc = ((t & k) == 0);
                if (desc ? (u < v) : (u > v)) { wl[t] = v; wl[ixj] = u; }
            }
            __syncthreads();
        }
    }

    if (t < MAXDET) {
        unsigned long long key = wl[t];
        if (key == 0ull) {
            ob[t * 4 + 0] = 0.0f; ob[t * 4 + 1] = 0.0f;
            ob[t * 4 + 2] = 0.0f; ob[t * 4 + 3] = 0.0f;
            os[t] = 0.0f; ol[t] = 0.0f;
        } else {
            int a = (int)(key & 0x3FFFull);
            int flat = 131071 - (int)((key >> 14) & 0x1FFFFull);
            int cmv = flat / TOPK;
            const float* bp = bx + (size_t)a * 4;
            ob[t * 4 + 0] = bp[0]; ob[t * 4 + 1] = bp[1];
            ob[t * 4 + 2] = bp[2]; ob[t * 4 + 3] = bp[3];
            os[t] = __uint_as_float((unsigned)(key >> 31));
            ol[t] = (float)(cmv + 1);
        }
    }
}

// ---------------------------------------------------------------- host launcher
extern "C" void kernel_launch(void* const* d_in, const int* in_sizes, int n_in,
                              void* d_out, int out_size, void* d_ws, size_t ws_size,
                              hipStream_t stream) {
    const void* logits  = d_in[0];   // [32, 8732, 91] f32
    const void* rel     = d_in[1];   // [32, 8732, 4]
    const void* anchors = d_in[2];   // [8732, 4]
    float* out = (float*)d_out;      // boxes|scores|labels flat, f32

    char* ws = (char*)d_ws;
    size_t off = 0;
    auto alloc = [&](size_t bytes) -> void* {
        void* p = ws + off;
        off = (off + bytes + 255) & ~(size_t)255;
        return p;
    };
    float* boxes  = (float*)alloc((size_t)B_N * A_N * 4 * sizeof(float));
    float* amax   = (float*)alloc((size_t)B_N * A_N * sizeof(float));
    float* denom  = (float*)alloc((size_t)B_N * A_N * sizeof(float));
    int*   flag   = (int*)alloc(256);
    int*   done   = (int*)alloc(256);
    unsigned long long* kkey = (unsigned long long*)alloc((size_t)B_N * CM1 * MAXDET * sizeof(unsigned long long));
    int* kcnt     = (int*)alloc((size_t)B_N * CM1 * sizeof(int));

    // transposed masked-SCORE buffer: [B][90][A] u32 — ~96 MiB. Only used if
    // the workspace can hold it; else fall back to the proven path.
    size_t scT_bytes = (size_t)B_N * CM1 * A_N * sizeof(unsigned);
    unsigned* scT = nullptr;
    if (off + scT_bytes <= ws_size) scT = (unsigned*)alloc(scT_bytes);

    int gridBA = (B_N * A_N + 255) / 256;

    k_sniff<<<1, 256, 0, stream>>>((const unsigned*)logits, flag, done);
    k_stats<<<gridBA, 256, 0, stream>>>(logits, rel, anchors, flag, amax, denom, boxes, scT);
    if (scT) {
        k_topknms_pre<<<B_N * CM1, NT, 0, stream>>>(scT, boxes, kkey, kcnt, out, done);
    } else {
        k_topknms<<<B_N * CM1, NT, 0, stream>>>(logits, flag, amax, denom, boxes, kkey, kcnt);
        k_merge<<<B_N, 256, 0, stream>>>(kkey, kcnt, boxes, out);
    }
}

// Round 9
// 555.257 us; speedup vs baseline: 1.3272x; 1.2495x over previous
//
#include <hip/hip_runtime.h>
#include <hip/hip_bf16.h>
#include <cstdint>
#include <cstddef>
#include <math.h>

// Match numpy f32 per-op rounding: no FMA contraction, no reassociation.
// (fmaf() below is explicit and unaffected by the pragma.)
#pragma clang fp contract(off)

#define A_N 8732
#define C_N 91
#define CM1 90
#define B_N 32
#define TOPK 400
#define MAXDET 200
#define NT 512                              /* threads in k_topknms */
#define CCAP 1024                           /* candidate-list capacity */
#define BBOX_CLIPF 4.135166556742356f       /* log(1000/16) cast to f32 */

// Exact predicate constant: for c = 0.45f (even mantissa),
// RN(x/y) > c  <=>  x > (c + 2^-26)*y  with the product exact in double
// (25-bit * 24-bit mantissa). Bit-equivalent to the IEEE f32 divide+compare.
#define IOU_M ((double)0.45f + 0x1p-26)

// 16B vector of floats with only 4B alignment guarantee (rows are 91 floats,
// so row bases are 4B- but not 16B-aligned).
typedef float f4u __attribute__((ext_vector_type(4), aligned(4)));

// Dual-path input load (reference is float32; sniff is insurance).
__device__ __forceinline__ float ldin(const void* p, size_t i, int isbf16) {
    if (isbf16) return __bfloat162float(((const __hip_bfloat16*)p)[i]);
    return ((const float*)p)[i];
}

// numpy SIMD f32 exp — bit-faithful (PROVEN bit-exact, absmax 0.0).
// DO NOT alter any constant or association.
__device__ __forceinline__ float np_expf(float x) {
    float q = rintf(x * 1.442695040f);
    float r = fmaf(q, -0.693359375f, x);
    r = fmaf(q, 2.12194440e-4f, r);
    float p = 1.9875691500E-4f;
    p = fmaf(p, r, 1.3981999507E-3f);
    p = fmaf(p, r, 8.3334519073E-3f);
    p = fmaf(p, r, 4.1665795894E-2f);
    p = fmaf(p, r, 1.6666665459E-1f);
    p = fmaf(p, r, 5.0000001201E-1f);
    p = fmaf(p, r, 1.0f);
    p = fmaf(p, r, 1.0f);
    return ldexpf(p, (int)q);
}

// ---------------------------------------------------------------- dtype sniff
__global__ void k_sniff(const unsigned* __restrict__ words, int* __restrict__ flag) {
    __shared__ int cnt_s;
    if (threadIdx.x == 0) cnt_s = 0;
    __syncthreads();
    int local = 0;
    for (int i = threadIdx.x; i < 4096; i += 256) {
        unsigned w = words[i];
        unsigned e = (w >> 7) & 0xFFu;
        if (e >= 100u && e <= 140u) local++;
    }
    atomicAdd(&cnt_s, local);
    __syncthreads();
    if (threadIdx.x == 0) flag[0] = (cnt_s > 2048) ? 1 : 0;
}

// ---------------------------------------------------------------- softmax + score + decode (fused)
// SINGLE pass over the logits row held in registers (proven fast, r8).
// Max chain, np_expf per class, exact numpy pairwise r[8] denom, then
// sc = e/res (identical quotient bits to the consumer's old divide) masked
// with > 0.01f and stored TRANSPOSED to scT[(b*90+c-1)*A + a]. amax/denom
// still written (fallback needs them). Decode fused (PROVEN bit-exact).
__global__ void k_stats(const void* __restrict__ logits,
                        const void* __restrict__ rel,
                        const void* __restrict__ anchors,
                        const int* __restrict__ flag,
                        float* __restrict__ amax,
                        float* __restrict__ denom,
                        float* __restrict__ boxes,
                        unsigned* __restrict__ scT) {
    int i = blockIdx.x * blockDim.x + threadIdx.x;
    if (i >= B_N * A_N) return;
    int bf = flag[0];
    size_t base = (size_t)i * C_N;
    int bb = i / A_N, aa = i - bb * A_N;
    unsigned* sbase = scT ? (scT + (size_t)bb * CM1 * A_N + aa) : (unsigned*)0;

    if (!bf) {
        const float* lp = (const float*)logits + base;
        float x[91];
        #pragma unroll
        for (int k = 0; k < 22; ++k) {
            f4u v = *(const f4u*)(lp + 4 * k);
            x[4 * k + 0] = v.x; x[4 * k + 1] = v.y;
            x[4 * k + 2] = v.z; x[4 * k + 3] = v.w;
        }
        x[88] = lp[88]; x[89] = lp[89]; x[90] = lp[90];

        float m = -INFINITY;
        #pragma unroll
        for (int c = 0; c < 91; ++c) m = fmaxf(m, x[c]);

        #pragma unroll
        for (int c = 0; c < 91; ++c) x[c] = np_expf(x[c] - m);   // x := e

        // exact numpy pairwise: r[j] = sum_k e[8k+j], k ascending (as before)
        float r[8];
        #pragma unroll
        for (int j = 0; j < 8; ++j) {
            float s = x[j];
            #pragma unroll
            for (int k = 1; k < 11; ++k) s += x[8 * k + j];
            r[j] = s;
        }
        float res = ((r[0] + r[1]) + (r[2] + r[3])) + ((r[4] + r[5]) + (r[6] + r[7]));
        res += x[88]; res += x[89]; res += x[90];
        amax[i]  = m;
        denom[i] = res;

        if (sbase) {
            #pragma unroll
            for (int c = 1; c < 91; ++c) {
                float sc = x[c] / res;       // identical quotient bits to the
                                             // consumer's old e/denom divide
                sbase[(size_t)(c - 1) * A_N] =
                    (sc > 0.01f) ? __float_as_uint(sc) : 0u;
            }
        }
    } else {
        // bf16 insurance path — scalar, same proven structure; emits sc bits.
        float m = -INFINITY;
        for (int c = 0; c < C_N; ++c) m = fmaxf(m, ldin(logits, base + c, bf));
        float r[8];
        for (int j = 0; j < 8; ++j) r[j] = np_expf(ldin(logits, base + j, bf) - m);
        for (int c = 8; c < 88; c += 8)
            for (int j = 0; j < 8; ++j) r[j] += np_expf(ldin(logits, base + c + j, bf) - m);
        float res = ((r[0] + r[1]) + (r[2] + r[3])) + ((r[4] + r[5]) + (r[6] + r[7]));
        res += np_expf(ldin(logits, base + 88, bf) - m);
        res += np_expf(ldin(logits, base + 89, bf) - m);
        res += np_expf(ldin(logits, base + 90, bf) - m);
        amax[i]  = m;
        denom[i] = res;
        if (sbase) {
            for (int c = 1; c < C_N; ++c) {
                float sc = np_expf(ldin(logits, base + c, bf) - m) / res;
                sbase[(size_t)(c - 1) * A_N] =
                    (sc > 0.01f) ? __float_as_uint(sc) : 0u;
            }
        }
    }

    // ---- fused box decode (PROVEN bit-exact expressions) ----
    {
        int a = aa;
        float ax1, ay1, ax2, ay2, r0, r1, r2, r3;
        if (!bf) {
            float4 av = ((const float4*)anchors)[a];
            float4 rv = ((const float4*)rel)[i];
            ax1 = av.x; ay1 = av.y; ax2 = av.z; ay2 = av.w;
            r0 = rv.x; r1 = rv.y; r2 = rv.z; r3 = rv.w;
        } else {
            ax1 = ldin(anchors, (size_t)a * 4 + 0, bf);
            ay1 = ldin(anchors, (size_t)a * 4 + 1, bf);
            ax2 = ldin(anchors, (size_t)a * 4 + 2, bf);
            ay2 = ldin(anchors, (size_t)a * 4 + 3, bf);
            r0 = ldin(rel, (size_t)i * 4 + 0, bf);
            r1 = ldin(rel, (size_t)i * 4 + 1, bf);
            r2 = ldin(rel, (size_t)i * 4 + 2, bf);
            r3 = ldin(rel, (size_t)i * 4 + 3, bf);
        }
        float wa = ax2 - ax1, ha = ay2 - ay1;
        float cxa = ax1 + 0.5f * wa, cya = ay1 + 0.5f * ha;
        float dx = r0 / 10.0f, dy = r1 / 10.0f;
        float dw = fminf(r2 / 5.0f, BBOX_CLIPF);
        float dh = fminf(r3 / 5.0f, BBOX_CLIPF);
        float cx = dx * wa + cxa, cy = dy * ha + cya;
        float w = np_expf(dw) * wa, h = np_expf(dh) * ha;
        float4 o;
        o.x = fminf(fmaxf(cx - 0.5f * w, 0.0f), 300.0f);
        o.y = fminf(fmaxf(cy - 0.5f * h, 0.0f), 300.0f);
        o.z = fminf(fmaxf(cx + 0.5f * w, 0.0f), 300.0f);
        o.w = fminf(fmaxf(cy + 0.5f * h, 0.0f), 300.0f);
        ((float4*)boxes)[i] = o;
    }
}

// ---------------------------------------------------------------- fused top-400 + per-class NMS
// v10: r8's kernel with the fused-merge tail REMOVED (the per-block
// __threadfence + cross-XCD merge reads serialized the memory system —
// occupancy 78->42%, +250us). Select fast path + on-demand ballot NMS kept
// (both proven, absmax 0.0). Ends at key emission.
__global__ __launch_bounds__(NT) void k_topknms_pre(const unsigned* __restrict__ scT,
                                                    const float* __restrict__ boxes,
                                                    unsigned long long* __restrict__ kkey,
                                                    int* __restrict__ kcnt) {
    __shared__ __align__(16) float4 nbq[TOPK];      // 6400 B
    __shared__ float sar[TOPK];                     // 1600 B
    __shared__ unsigned long long wlist[512];       // 4096 B
    __shared__ unsigned long long cand[CCAP];       // 8192 B
    __shared__ unsigned hist[1024];                 // 4096 B
    __shared__ unsigned long long fsup[8];
    __shared__ unsigned long long ksv[8];
    __shared__ unsigned sel_b;
    __shared__ int sel_rem;
    __shared__ int nreal_s;
    __shared__ int eqlist[64];
    __shared__ int eqn, nsel, candn, total_s;

    int bc = blockIdx.x;
    int b  = bc / CM1;
    int cm = bc % CM1;                       // class row 0..89 (logit col cm+1)
    int t  = threadIdx.x;

    const unsigned* srow = scT + (size_t)bc * A_N;
    const uint4* srow4 = (const uint4*)srow;

    // ---- phase 0: stream masked score bits, build level-1 histogram.
    if (t == 0) { eqn = 0; nsel = 0; candn = 0; total_s = 0; }
    for (int q = t; q < 1024; q += NT) hist[q] = 0u;
    __syncthreads();
    for (int k = t; k < A_N / 4; k += NT) {
        uint4 v = srow4[k];
        if (v.x) atomicAdd(&hist[(v.x >> 16) & 0x3FFu], 1u);
        if (v.y) atomicAdd(&hist[(v.y >> 16) & 0x3FFu], 1u);
        if (v.z) atomicAdd(&hist[(v.z >> 16) & 0x3FFu], 1u);
        if (v.w) atomicAdd(&hist[(v.w >> 16) & 0x3FFu], 1u);
    }
    __syncthreads();

    // ---- level-1 scan: suffix sums give BOTH nreal and the 400th bucket.
    if (t < 64) {
        unsigned s = 0;
        #pragma unroll
        for (int q = 0; q < 16; ++q) s += hist[16 * t + q];
        unsigned suf = s;
        for (int o = 1; o < 64; o <<= 1) {
            unsigned vv = __shfl_down(suf, o);
            if (t + o < 64) suf += vv;
        }
        if (t == 0) nreal_s = (int)suf;
        unsigned cum = suf - s;
        for (int q = 15; q >= 0; --q) {
            unsigned h = hist[16 * t + q];
            if ((int)cum < TOPK && TOPK <= (int)(cum + h)) {
                sel_b = (unsigned)(16 * t + q);
                sel_rem = TOPK - (int)cum;
            }
            cum += h;
        }
    }
    __syncthreads();
    int nreal = nreal_s;
    bool sel_path = (nreal >= TOPK);         // block-uniform
    unsigned selL1 = sel_b;                  // valid iff sel_path
    unsigned prefix1 = (0xFu << 10) | selL1;
    __syncthreads();

    // ---- pass B: classify. bucket>selL1 -> wlist; bucket==selL1 -> cand
    // (+ level-2 histogram for the slow path); !sel_path: all nonzero -> wlist.
    if (sel_path) { for (int q = t; q < 1024; q += NT) hist[q] = 0u; }
    __syncthreads();
    for (int k = t; k < A_N / 4; k += NT) {
        uint4 vv = srow4[k];
        unsigned va[4] = {vv.x, vv.y, vv.z, vv.w};
        #pragma unroll
        for (int c = 0; c < 4; ++c) {
            unsigned v = va[c];
            if (!v) continue;
            unsigned a = (unsigned)(4 * k + c);
            if (sel_path) {
                unsigned bkt = (v >> 16) & 0x3FFu;
                if (bkt > selL1) {
                    int slot = atomicAdd(&nsel, 1);
                    if (slot < 512)
                        wlist[slot] = ((unsigned long long)v << 32) | (unsigned)(~a);
                } else if (bkt == selL1) {
                    int s2 = atomicAdd(&candn, 1);
                    if (s2 < CCAP)
                        cand[s2] = ((unsigned long long)v << 32) | (unsigned)(~a);
                    atomicAdd(&hist[(v >> 6) & 0x3FFu], 1u);
                }
            } else {
                int slot = atomicAdd(&nsel, 1);
                if (slot < 512)
                    wlist[slot] = ((unsigned long long)v << 32) | (unsigned)(~a);
            }
        }
    }
    __syncthreads();

    if (sel_path) {
        int ngt = nsel;                      // strictly-greater count (<400)
        int cn  = candn;                     // boundary-bucket count
        bool fast = (cn <= CCAP) && (ngt + cn <= 512);
        if (fast) {
            // exact: sort of (gt ∪ bucket) desc by (score, anchor asc) and
            // truncation to 400 == proven selection + tie rule.
            for (int q = t; q < cn; q += NT) wlist[ngt + q] = cand[q];
            __syncthreads();
            if (t == 0) nsel = ngt + cn;
            __syncthreads();
        } else {
            // ---- slow path (verbatim proven logic) ----
            bool ovf = (cn > CCAP);
            if (t < 64) {
                int rem = sel_rem;
                unsigned s = 0;
                #pragma unroll
                for (int q = 0; q < 16; ++q) s += hist[16 * t + q];
                unsigned suf = s;
                for (int o = 1; o < 64; o <<= 1) {
                    unsigned vv = __shfl_down(suf, o);
                    if (t + o < 64) suf += vv;
                }
                unsigned cum = suf - s;
                for (int q = 15; q >= 0; --q) {
                    unsigned h = hist[16 * t + q];
                    if ((int)cum < rem && rem <= (int)(cum + h)) {
                        sel_b = (unsigned)(16 * t + q);
                        sel_rem = rem - (int)cum;
                    }
                    cum += h;
                }
            }
            __syncthreads();
            unsigned prefix2 = (prefix1 << 10) | sel_b;

            if (t < 64) hist[t] = 0u;
            __syncthreads();
            if (!ovf) {
                int cc = cn < CCAP ? cn : CCAP;
                for (int q = t; q < cc; q += NT) {
                    unsigned v = (unsigned)(cand[q] >> 32);
                    if ((v >> 6) == prefix2) atomicAdd(&hist[v & 0x3Fu], 1u);
                }
            } else {
                for (int a = t; a < A_N; a += NT) {
                    unsigned v = srow[a];
                    if (v && (v >> 6) == prefix2) atomicAdd(&hist[v & 0x3Fu], 1u);
                }
            }
            __syncthreads();
            if (t == 0) {
                int rem = sel_rem;
                unsigned cum = 0;
                for (int bq = 63; bq >= 0; --bq) {
                    unsigned h = hist[bq];
                    if ((int)cum < rem && rem <= (int)(cum + h)) {
                        sel_b = (unsigned)bq;
                        sel_rem = rem - (int)cum;
                        break;
                    }
                    cum += h;
                }
            }
            __syncthreads();
            unsigned sstar = (prefix2 << 6) | sel_b;
            int teq = sel_rem;

            if (!ovf) {
                int cc = cn < CCAP ? cn : CCAP;
                for (int q = t; q < cc; q += NT) {
                    unsigned long long cv = cand[q];
                    unsigned v = (unsigned)(cv >> 32);
                    if (v > sstar) {
                        int slot = atomicAdd(&nsel, 1);
                        if (slot < 512) wlist[slot] = cv;
                    } else if (v == sstar) {
                        int s2 = atomicAdd(&eqn, 1);
                        if (s2 < 64) eqlist[s2] = (int)(~(unsigned)cv);
                    }
                }
            } else {
                for (int a = t; a < A_N; a += NT) {
                    unsigned v = srow[a];
                    if (!v) continue;
                    if ((v >> 16) == prefix1) {
                        if (v > sstar) {
                            int slot = atomicAdd(&nsel, 1);
                            if (slot < 512)
                                wlist[slot] = ((unsigned long long)v << 32) |
                                              (unsigned)(~(unsigned)a);
                        } else if (v == sstar) {
                            int s2 = atomicAdd(&eqn, 1);
                            if (s2 < 64) eqlist[s2] = a;
                        }
                    }
                }
            }
            __syncthreads();
            if (t == 0) {
                int n = eqn < 64 ? eqn : 64; // same 64-cap as proven kernel
                for (int i2 = 1; i2 < n; ++i2) {
                    int v2 = eqlist[i2], j2 = i2 - 1;
                    while (j2 >= 0 && eqlist[j2] > v2) { eqlist[j2 + 1] = eqlist[j2]; --j2; }
                    eqlist[j2 + 1] = v2;
                }
                int tq = teq < n ? teq : n;
                int bse = nsel;
                for (int q2 = 0; q2 < tq; ++q2) {
                    int slot = bse + q2;
                    if (slot < 512)
                        wlist[slot] = ((unsigned long long)sstar << 32) |
                                      (unsigned)(~(unsigned)eqlist[q2]);
                }
                nsel = bse + tq;
            }
            __syncthreads();
        }
    }
    int ns = nsel < 512 ? nsel : 512;
    if (t >= ns) wlist[t] = 0ull;
    __syncthreads();

    // ---- bitonic sort 512 desc, register-resident; shfl_xor for j<=32,
    // LDS exchange only for j>=64. Same network => identical permutation.
    {
        unsigned long long u = wlist[t];
        for (int k = 2; k <= 512; k <<= 1) {
            bool up = ((t & k) == 0);
            for (int j = k >> 1; j >= 64; j >>= 1) {
                __syncthreads();
                wlist[t] = u;
                __syncthreads();
                unsigned long long v = wlist[t ^ j];
                bool takeMax = (((t & j) == 0) == up);
                u = takeMax ? (u > v ? u : v) : (u < v ? u : v);
            }
            for (int j = ((k >> 1) < 64 ? (k >> 1) : 32); j > 0; j >>= 1) {
                unsigned long long v = __shfl_xor(u, j);
                bool takeMax = (((t & j) == 0) == up);
                u = takeMax ? (u > v ? u : v) : (u < v ? u : v);
            }
        }
        __syncthreads();
        wlist[t] = u;
        __syncthreads();
    }

    // ---- per-class NMS on the sorted top-400: r6's PROVEN on-demand form ----
    int m = ns < TOPK ? ns : TOPK;
    float offc = (float)(cm + 1) * 301.0f;
    if (t < m) {
        unsigned aidx = ~(unsigned)(wlist[t] & 0xFFFFFFFFull);
        const float* bp = boxes + ((size_t)b * A_N + aidx) * 4;
        float4 q;
        q.x = bp[0] + offc; q.y = bp[1] + offc;   // same exprs as proven code
        q.z = bp[2] + offc; q.w = bp[3] + offc;
        nbq[t] = q;
        sar[t] = (q.z - q.x) * (q.w - q.y);       // == bar[t] bits
    }
    if (t < 8) { fsup[t] = 0ull; ksv[t] = 0ull; }
    __syncthreads();

    int nch = (m + 63) >> 6;
    for (int g = 0; g < nch; ++g) {
        // wave 0: greedy scan of chunk g; masks of kept rows built on the
        // fly via ballot (lane = column within chunk). Decisions identical
        // to the proven serial scan.
        if (t < 64) {
            int bse = 64 * g;
            int jmax = m - bse; if (jmax > 64) jmax = 64;
            bool valid = t < jmax;
            float4 cb = valid ? nbq[bse + t] : make_float4(0.f, 0.f, 0.f, 0.f);
            float car = valid ? sar[bse + t] : 0.0f;
            unsigned long long sup = fsup[g], kv = 0ull;
            unsigned long long rem =
                ((jmax == 64) ? ~0ull : ((1ull << jmax) - 1ull)) & ~sup;
            while (rem) {
                int j = __builtin_ctzll(rem);    // next non-suppressed row
                float rx1 = __shfl(cb.x, j), ry1 = __shfl(cb.y, j);
                float rx2 = __shfl(cb.z, j), ry2 = __shfl(cb.w, j);
                float ra  = __shfl(car, j);
                bool p = false;
                if (valid && t > j) {            // strictly j<col, like j>i2
                    float lx = fmaxf(rx1, cb.x), ly = fmaxf(ry1, cb.y);
                    float rx = fminf(rx2, cb.z), ry = fminf(ry2, cb.w);
                    float ww = fmaxf(rx - lx, 0.0f), hh = fmaxf(ry - ly, 0.0f);
                    float inter = ww * hh;
                    float U = ra + car - inter + 1e-9f;   // row area first
                    p = ((double)inter > IOU_M * (double)U);
                }
                unsigned long long wj = __ballot(p);
                kv |= 1ull << j;
                sup |= wj;
                rem &= ~(sup | (1ull << j));
            }
            if (t == 0) { ksv[g] = kv; total_s += __popcll(kv); }
        }
        __syncthreads();
        if (total_s >= MAXDET) break;        // uniform; rows past the 200th
                                             // kept are never emitted anyway
        if (g + 1 < nch) {
            // waves 1..: future-word suppression = OR over kept rows of
            // chunk g (broadcast LDS reads; lane = column of word h).
            int w = t >> 6, l = t & 63;
            int h = g + 1 + w;
            if (h < nch) {
                unsigned long long kv = ksv[g];
                int jmax2 = m - 64 * h; if (jmax2 > 64) jmax2 = 64;
                bool v2 = l < jmax2;
                float4 cbl = v2 ? nbq[64 * h + l] : make_float4(0.f, 0.f, 0.f, 0.f);
                float cal = v2 ? sar[64 * h + l] : 0.0f;
                bool acc = false;
                unsigned long long rr = kv;
                while (rr) {
                    int r = __builtin_ctzll(rr); rr &= rr - 1;
                    float4 rq = nbq[64 * g + r];     // wave-uniform broadcast
                    float rar = sar[64 * g + r];
                    if (v2 && !acc) {
                        float lx = fmaxf(rq.x, cbl.x), ly = fmaxf(rq.y, cbl.y);
                        float rx = fminf(rq.z, cbl.z), ry = fminf(rq.w, cbl.w);
                        float ww = fmaxf(rx - lx, 0.0f), hh = fmaxf(ry - ly, 0.0f);
                        float inter = ww * hh;
                        float U = rar + cal - inter + 1e-9f;
                        acc = ((double)inter > IOU_M * (double)U);
                    }
                }
                unsigned long long wd = __ballot(acc);
                if (l == 0) fsup[h] |= wd;
            }
        }
        __syncthreads();
    }

    // rank-parallel emission (kept order == row order == serial order)
    if (t < 64) {
        int l = t, basek = 0;
        for (int g = 0; g < nch; ++g) {
            unsigned long long kv = ksv[g];
            int row = 64 * g + l;
            if ((kv >> l) & 1ull) {
                int rank = basek + __popcll(kv & ((1ull << l) - 1ull));
                if (rank < MAXDET) {
                    unsigned long long wv = wlist[row];
                    unsigned sbts = (unsigned)(wv >> 32);
                    unsigned aa2  = ~(unsigned)wv;        // anchor, <16384
                    int flat = cm * TOPK + row;
                    unsigned long long key =
                        ((unsigned long long)sbts << 31) |
                        ((unsigned long long)(131071 - flat) << 14) |
                        (unsigned long long)aa2;
                    kkey[(size_t)bc * MAXDET + rank] = key;
                }
            }
            basek += __popcll(kv);
        }
        if (l == 0) kcnt[bc] = total_s < MAXDET ? total_s : MAXDET;
    }
}

// ---------------------------------------------------------------- FALLBACK top-400 + NMS
// Verbatim proven kernel (used only if the workspace can't hold scT).
__global__ __launch_bounds__(NT) void k_topknms(const void* __restrict__ logits,
                                                const int* __restrict__ flag,
                                                const float* __restrict__ amax,
                                                const float* __restrict__ denom,
                                                const float* __restrict__ boxes,
                                                unsigned long long* __restrict__ kkey,
                                                int* __restrict__ kcnt) {
    __shared__ union {
        unsigned sbits[A_N];
        unsigned long long msk[TOPK * 7];
    } su;
    __shared__ unsigned long long wlist[512];
    __shared__ float bx1[TOPK], by1[TOPK], bx2[TOPK], by2[TOPK], bar[TOPK];
    __shared__ int wred[NT / 64];
    __shared__ unsigned bcast_p;
    __shared__ int bcast_rem;
    __shared__ int eqlist[64];
    __shared__ int eqn;
    __shared__ int bcast_athr;
    __shared__ int nsel;

    int bc = blockIdx.x;
    int b  = bc / CM1;
    int cm = bc % CM1;
    int bf = flag[0];
    int t  = threadIdx.x;

    for (int a = t; a < A_N; a += NT) {
        size_t base = (size_t)b * A_N + a;
        float e  = np_expf(ldin(logits, base * C_N + (cm + 1), bf) - amax[base]);
        float sc = e / denom[base];
        su.sbits[a] = (sc > 0.01f) ? __float_as_uint(sc) : 0u;
    }
    if (t == 0) { eqn = 0; nsel = 0; }
    __syncthreads();

    {
        int c0 = 0;
        for (int a = t; a < A_N; a += NT) c0 += (su.sbits[a] != 0u);
        for (int o = 32; o; o >>= 1) c0 += __shfl_down(c0, o);
        if ((t & 63) == 0) wred[t >> 6] = c0;
        __syncthreads();
        if (t == 0) {
            int tot = 0;
            for (int wv = 0; wv < NT / 64; ++wv) tot += wred[wv];
            bcast_rem = tot;
        }
        __syncthreads();
    }
    int nreal = bcast_rem;
    __syncthreads();

    unsigned sstar = 0u;
    int teq = 0;
    if (nreal >= TOPK) {
        unsigned p = 0x3C000000u;
        int rem = TOPK;
        for (int bit = 25; bit >= 0; --bit) {
            unsigned q = p | (1u << bit);
            int cnt = 0;
            for (int a = t; a < A_N; a += NT) cnt += ((su.sbits[a] >> bit) == (q >> bit));
            for (int o = 32; o; o >>= 1) cnt += __shfl_down(cnt, o);
            if ((t & 63) == 0) wred[t >> 6] = cnt;
            __syncthreads();
            if (t == 0) {
                int tot = 0;
                for (int wv = 0; wv < NT / 64; ++wv) tot += wred[wv];
                if (tot >= rem) { bcast_p = q; bcast_rem = rem; }
                else            { bcast_p = p; bcast_rem = rem - tot; }
            }
            __syncthreads();
            p = bcast_p; rem = bcast_rem;
            __syncthreads();
        }
        sstar = p;
        teq = rem;
        for (int a = t; a < A_N; a += NT) {
            if (su.sbits[a] == sstar) {
                int slot = atomicAdd(&eqn, 1);
                if (slot < 64) eqlist[slot] = a;
            }
        }
        __syncthreads();
        if (t == 0) {
            int n = eqn < 64 ? eqn : 64;
            for (int i = 1; i < n; ++i) {
                int v = eqlist[i], j = i - 1;
                while (j >= 0 && eqlist[j] > v) { eqlist[j + 1] = eqlist[j]; --j; }
                eqlist[j + 1] = v;
            }
            int tq = teq < n ? teq : n;
            bcast_athr = (tq > 0) ? eqlist[tq - 1] : -1;
        }
        __syncthreads();
    }
    int athr = (nreal >= TOPK) ? bcast_athr : -1;
    __syncthreads();

    for (int a = t; a < A_N; a += NT) {
        unsigned v = su.sbits[a];
        bool sel;
        if (nreal >= TOPK)
            sel = (v > sstar) || (v == sstar && a <= athr);
        else
            sel = (v != 0u);
        if (sel) {
            int slot = atomicAdd(&nsel, 1);
            if (slot < 512)
                wlist[slot] = ((unsigned long long)v << 32) | (unsigned)(~(unsigned)a);
        }
    }
    __syncthreads();
    int ns = nsel < 512 ? nsel : 512;
    if (t < 512 && t >= ns) wlist[t] = 0ull;
    __syncthreads();

    for (int k = 2; k <= 512; k <<= 1) {
        for (int j = k >> 1; j > 0; j >>= 1) {
            int ixj = t ^ j;
            if (ixj > t) {
                unsigned long long u = wlist[t], v = wlist[ixj];
                bool desc = ((t & k) == 0);
                if (desc ? (u < v) : (u > v)) { wlist[t] = v; wlist[ixj] = u; }
            }
            __syncthreads();
        }
    }

    int m = ns < TOPK ? ns : TOPK;
    float offc = (float)(cm + 1) * 301.0f;
    if (t < m) {
        unsigned aidx = ~(unsigned)(wlist[t] & 0xFFFFFFFFull);
        const float* bp = boxes + ((size_t)b * A_N + aidx) * 4;
        float x1 = bp[0] + offc, y1 = bp[1] + offc;
        float x2 = bp[2] + offc, y2 = bp[3] + offc;
        bx1[t] = x1; by1[t] = y1; bx2[t] = x2; by2[t] = y2;
        bar[t] = (x2 - x1) * (y2 - y1);
    }
    __syncthreads();

    if (t < m) {
        unsigned long long w[7] = {0, 0, 0, 0, 0, 0, 0};
        float x1 = bx1[t], y1 = by1[t], x2 = bx2[t], y2 = by2[t], a1 = bar[t];
        for (int j = t + 1; j < m; ++j) {
            float lx = fmaxf(x1, bx1[j]), ly = fmaxf(y1, by1[j]);
            float rx = fminf(x2, bx2[j]), ry = fminf(y2, by2[j]);
            float ww = fmaxf(rx - lx, 0.0f), hh = fmaxf(ry - ly, 0.0f);
            float inter = ww * hh;
            float iou = inter / (a1 + bar[j] - inter + 1e-9f);
            if (iou > 0.45f) w[j >> 6] |= 1ull << (j & 63);
        }
        for (int k2 = 0; k2 < 7; ++k2) su.msk[t * 7 + k2] = w[k2];
    }
    __syncthreads();

    if (t == 0) {
        unsigned long long sup[7] = {0, 0, 0, 0, 0, 0, 0};
        int cnt = 0;
        for (int i = 0; i < m; ++i) {
            if (!((sup[i >> 6] >> (i & 63)) & 1ull)) {
                unsigned long long wv = wlist[i];
                unsigned sb2 = (unsigned)(wv >> 32);
                unsigned a  = ~(unsigned)wv;
                int flat = cm * TOPK + i;
                unsigned long long key =
                    ((unsigned long long)sb2 << 31) |
                    ((unsigned long long)(131071 - flat) << 14) |
                    (unsigned long long)a;
                kkey[(size_t)bc * MAXDET + cnt] = key;
                cnt++;
                if (cnt == MAXDET) break;
                const unsigned long long* r = &su.msk[i * 7];
                for (int k2 = 0; k2 < 7; ++k2) sup[k2] |= r[k2];
            }
        }
        kcnt[bc] = cnt;
    }
}

// ---------------------------------------------------------------- parallel per-image top-200
// v3: total from kcnt sum (no key-count pass); EARLY-EXIT radix — any T with
// count(>=T)==200 is sufficient (keys unique): when the boundary bucket is
// taken whole (rem==h), T = bucket lower bound, stop. Typically exits after
// 1-2 levels instead of 7. Gather, bitonic sort 256 desc, emit. Bit-identical.
__global__ __launch_bounds__(256) void k_merge(const unsigned long long* __restrict__ kkey,
                                               const int* __restrict__ kcnt,
                                               const float* __restrict__ boxes,
                                               float* __restrict__ out) {
    __shared__ unsigned hist[1024];
    __shared__ unsigned long long wl[256];
    __shared__ int kc[CM1];
    __shared__ int tot_s;
    __shared__ unsigned selb_s, selh_s;
    __shared__ int selrem_s;
    __shared__ int gcnt;
    __shared__ unsigned long long T_s;

    int b = blockIdx.x;
    int t = threadIdx.x;
    const unsigned long long* keys = kkey + (size_t)b * (CM1 * MAXDET);
    const float* bx = boxes + (size_t)b * A_N * 4;
    float* ob = out + (size_t)b * MAXDET * 4;
    float* os = out + (size_t)B_N * MAXDET * 4 + (size_t)b * MAXDET;
    float* ol = out + (size_t)B_N * MAXDET * 5 + (size_t)b * MAXDET;

    if (t < CM1) kc[t] = kcnt[b * CM1 + t];
    if (t == 0) { gcnt = 0; T_s = 0ull; }
    __syncthreads();
    if (t == 0) {                           // total = sum of per-class counts
        int tot = 0;
        for (int c = 0; c < CM1; ++c) tot += kc[c];
        tot_s = tot;
        selrem_s = MAXDET;
    }
    __syncthreads();
    int total = tot_s;

    if (total > MAXDET) {
        unsigned long long prefix = 0ull;
        for (int l = 0; l < 7; ++l) {
            int width = (l == 6) ? 2 : 10;
            int shift = (l == 6) ? 0 : (52 - 10 * l);
            int nb = 1 << width;
            for (int q = t; q < nb; q += 256) hist[q] = 0u;
            __syncthreads();
            for (int idx = t; idx < CM1 * MAXDET; idx += 256) {
                int c = idx / MAXDET;
                if (idx - c * MAXDET < kc[c]) {
                    unsigned long long key = keys[idx];
                    if ((key >> (shift + width)) == prefix)
                        atomicAdd(&hist[(unsigned)(key >> shift) & (unsigned)(nb - 1)], 1u);
                }
            }
            __syncthreads();
            if (nb >= 64) {
                if (t < 64) {
                    int rem = selrem_s;
                    int per = nb / 64;
                    unsigned s = 0;
                    for (int q = 0; q < per; ++q) s += hist[per * t + q];
                    unsigned suf = s;
                    for (int o = 1; o < 64; o <<= 1) {
                        unsigned vv = __shfl_down(suf, o);
                        if (t + o < 64) suf += vv;
                    }
                    unsigned cum = suf - s;
                    for (int q = per - 1; q >= 0; --q) {
                        unsigned h = hist[per * t + q];
                        if ((int)cum < rem && rem <= (int)(cum + h)) {
                            selb_s = (unsigned)(per * t + q);
                            selrem_s = rem - (int)cum;
                            selh_s = h;
                        }
                        cum += h;
                    }
                }
            } else if (t == 0) {
                int rem = selrem_s;
                unsigned cum = 0;
                for (int bq = nb - 1; bq >= 0; --bq) {
                    unsigned h = hist[bq];
                    if ((int)cum < rem && rem <= (int)(cum + h)) {
                        selb_s = (unsigned)bq;
                        selrem_s = rem - (int)cum;
                        selh_s = h;
                        break;
                    }
                    cum += h;
                }
            }
            __syncthreads();
            prefix = (prefix << width) | (unsigned long long)selb_s;
            // EARLY EXIT: whole boundary bucket taken -> count(>= bucket_lo)
            // == 200 exactly; T = bucket lower bound suffices (keys unique).
            bool whole = (selrem_s == (int)selh_s);
            __syncthreads();
            if (whole || l == 6) {
                if (t == 0) T_s = prefix << shift;
                break;
            }
        }
        __syncthreads();
    }
    unsigned long long T = T_s;

    wl[t] = 0ull;
    __syncthreads();
    for (int idx = t; idx < CM1 * MAXDET; idx += 256) {
        int c = idx / MAXDET;
        if (idx - c * MAXDET < kc[c]) {
            unsigned long long key = keys[idx];
            if (total <= MAXDET ? true : (key >= T)) {
                int s = atomicAdd(&gcnt, 1);
                if (s < 256) wl[s] = key;
            }
        }
    }
    __syncthreads();

    for (int k = 2; k <= 256; k <<= 1) {
        for (int j = k >> 1; j > 0; j >>= 1) {
            int ixj = t ^ j;
            if (ixj > t) {
                unsigned long long u = wl[t], v = wl[ixj];
                bool desc = ((t & k) == 0);
                if (desc ? (u < v) : (u > v)) { wl[t] = v; wl[ixj] = u; }
            }
            __syncthreads();
        }
    }

    if (t < MAXDET) {
        unsigned long long key = wl[t];
        if (key == 0ull) {
            ob[t * 4 + 0] = 0.0f; ob[t * 4 + 1] = 0.0f;
            ob[t * 4 + 2] = 0.0f; ob[t * 4 + 3] = 0.0f;
            os[t] = 0.0f; ol[t] = 0.0f;
        } else {
            int a = (int)(key & 0x3FFFull);
            int flat = 131071 - (int)((key >> 14) & 0x1FFFFull);
            int cmv = flat / TOPK;
            const float* bp = bx + (size_t)a * 4;
            ob[t * 4 + 0] = bp[0]; ob[t * 4 + 1] = bp[1];
            ob[t * 4 + 2] = bp[2]; ob[t * 4 + 3] = bp[3];
            os[t] = __uint_as_float((unsigned)(key >> 31));
            ol[t] = (float)(cmv + 1);
        }
    }
}

// ---------------------------------------------------------------- host launcher
extern "C" void kernel_launch(void* const* d_in, const int* in_sizes, int n_in,
                              void* d_out, int out_size, void* d_ws, size_t ws_size,
                              hipStream_t stream) {
    const void* logits  = d_in[0];   // [32, 8732, 91] f32
    const void* rel     = d_in[1];   // [32, 8732, 4]
    const void* anchors = d_in[2];   // [8732, 4]
    float* out = (float*)d_out;      // boxes|scores|labels flat, f32

    char* ws = (char*)d_ws;
    size_t off = 0;
    auto alloc = [&](size_t bytes) -> void* {
        void* p = ws + off;
        off = (off + bytes + 255) & ~(size_t)255;
        return p;
    };
    float* boxes  = (float*)alloc((size_t)B_N * A_N * 4 * sizeof(float));
    float* amax   = (float*)alloc((size_t)B_N * A_N * sizeof(float));
    float* denom  = (float*)alloc((size_t)B_N * A_N * sizeof(float));
    int*   flag   = (int*)alloc(256);
    unsigned long long* kkey = (unsigned long long*)alloc((size_t)B_N * CM1 * MAXDET * sizeof(unsigned long long));
    int* kcnt     = (int*)alloc((size_t)B_N * CM1 * sizeof(int));

    // transposed masked-SCORE buffer: [B][90][A] u32 — ~96 MiB. Only used if
    // the workspace can hold it; else fall back to the proven path.
    size_t scT_bytes = (size_t)B_N * CM1 * A_N * sizeof(unsigned);
    unsigned* scT = nullptr;
    if (off + scT_bytes <= ws_size) scT = (unsigned*)alloc(scT_bytes);

    int gridBA = (B_N * A_N + 255) / 256;

    k_sniff<<<1, 256, 0, stream>>>((const unsigned*)logits, flag);
    k_stats<<<gridBA, 256, 0, stream>>>(logits, rel, anchors, flag, amax, denom, boxes, scT);
    if (scT)
        k_topknms_pre<<<B_N * CM1, NT, 0, stream>>>(scT, boxes, kkey, kcnt);
    else
        k_topknms<<<B_N * CM1, NT, 0, stream>>>(logits, flag, amax, denom, boxes, kkey, kcnt);
    k_merge<<<B_N, 256, 0, stream>>>(kkey, kcnt, boxes, out);
}